// Round 3
// baseline (273.648 us; speedup 1.0000x reference)
//
#include <hip/hip_runtime.h>
#include <math.h>

#define EPSf 1e-10f
#define IMG_N 64
#define IMG_H 512
#define IMG_W 512
#define KBLK 4096                  // 64x64 blocks per image
#define TOTAL_BLK (IMG_N * KBLK)   // 262144
#define WG 256
#define NWG (TOTAL_BLK / WG)       // 1024
#define CHUNKS 16                  // workgroups per image in kC

__device__ __forceinline__ float wave_red(float v) {
#pragma unroll
    for (int o = 32; o > 0; o >>= 1) v += __shfl_down(v, o, 64);
    return v;
}

// ---------------- kernel A: per-block DC amplitude of target, partial sums ----
__global__ __launch_bounds__(WG) void kA(const float* __restrict__ tgt,
                                         float* __restrict__ partA) {
    int gid = blockIdx.x * WG + threadIdx.x;
    int n = gid >> 12;
    int k = gid & 4095;
    int bi = k >> 6, bj = k & 63;
    const float* p = tgt + (size_t)n * (IMG_H * IMG_W) + (size_t)(bi * 8) * IMG_W + bj * 8;
    float s = 0.f;
#pragma unroll
    for (int r = 0; r < 8; r++) {
        float4 a = *(const float4*)(p + (size_t)r * IMG_W);
        float4 b = *(const float4*)(p + (size_t)r * IMG_W + 4);
        s += ((a.x + a.y) + (a.z + a.w)) + ((b.x + b.y) + (b.z + b.w));
    }
    float dc = s * (1.0f / 64.0f);                 // rfft2 DC / b^2
    float amp = sqrtf((dc + EPSf) * (dc + EPSf) + EPSf * EPSf);
    float wv = wave_red(amp);
    __shared__ float red[4];
    if ((threadIdx.x & 63) == 0) red[threadIdx.x >> 6] = wv;
    __syncthreads();
    if (threadIdx.x == 0) partA[blockIdx.x] = (red[0] + red[1]) + (red[2] + red[3]);
}

// ---------------- kernel B: reduce 1024 partials -> avg_lum -------------------
__global__ __launch_bounds__(1024) void kB(const float* __restrict__ partA,
                                           float* __restrict__ avgOut) {
    float v = partA[threadIdx.x];
    float wv = wave_red(v);
    __shared__ float red[16];
    if ((threadIdx.x & 63) == 0) red[threadIdx.x >> 6] = wv;
    __syncthreads();
    if (threadIdx.x == 0) {
        float s = 0.f;
#pragma unroll
        for (int i = 0; i < 16; i++) s += red[i];
        avgOut[0] = s * (1.0f / (float)TOTAL_BLK);
    }
}

// row real FFT-8, compact 8-float output, scaled by 1/64
// y = [c0, c1r, c1i, c2r, c2i, c3r, c3i, c4]
__device__ __forceinline__ void rowfft8(float4 a, float4 b, float y[8]) {
    const float C = 0.70710678118654752440f;
    const float S = 1.0f / 64.0f;
    float s02 = a.x + b.x, d02 = a.x - b.x;
    float s26 = a.z + b.z, d26 = a.z - b.z;
    float s13 = a.y + b.y, d13 = a.y - b.y;
    float s37 = a.w + b.w, d37 = a.w - b.w;
    float e0 = s02 + s26, e2 = s02 - s26;
    float o0 = s13 + s37, o2 = s13 - s37;
    float cp = C * (d13 - d37), cm = C * (d13 + d37);
    y[0] = S * (e0 + o0);
    y[1] = S * (d02 + cp);
    y[2] = S * (-d26 - cm);
    y[3] = S * e2;
    y[4] = S * (-o2);
    y[5] = S * (d02 - cp);
    y[6] = S * (d26 - cm);
    y[7] = S * (e0 - o0);
}

// complex FFT-8 (unscaled)
__device__ __forceinline__ void cfft8(const float xr[8], const float xi[8],
                                      float Xr[8], float Xi[8]) {
    const float C = 0.70710678118654752440f;
    float t0r = xr[0] + xr[4], t0i = xi[0] + xi[4];
    float t1r = xr[0] - xr[4], t1i = xi[0] - xi[4];
    float t2r = xr[2] + xr[6], t2i = xi[2] + xi[6];
    float t3r = xr[2] - xr[6], t3i = xi[2] - xi[6];
    float E0r = t0r + t2r, E0i = t0i + t2i;
    float E2r = t0r - t2r, E2i = t0i - t2i;
    float E1r = t1r + t3i, E1i = t1i - t3r;   // t1 - i*t3
    float E3r = t1r - t3i, E3i = t1i + t3r;   // t1 + i*t3
    float u0r = xr[1] + xr[5], u0i = xi[1] + xi[5];
    float u1r = xr[1] - xr[5], u1i = xi[1] - xi[5];
    float u2r = xr[3] + xr[7], u2i = xi[3] + xi[7];
    float u3r = xr[3] - xr[7], u3i = xi[3] - xi[7];
    float O0r = u0r + u2r, O0i = u0i + u2i;
    float O2r = u0r - u2r, O2i = u0i - u2i;
    float O1r = u1r + u3i, O1i = u1i - u3r;
    float O3r = u1r - u3i, O3i = u1i + u3r;
    float W1r = C * (O1r + O1i), W1i = C * (O1i - O1r);  // W8^1 * O1
    float W2r = O2i,             W2i = -O2r;             // -i * O2
    float W3r = C * (O3i - O3r), W3i = -C * (O3r + O3i); // W8^3 * O3
    Xr[0] = E0r + O0r; Xi[0] = E0i + O0i;
    Xr[1] = E1r + W1r; Xi[1] = E1i + W1i;
    Xr[2] = E2r + W2r; Xi[2] = E2i + W2i;
    Xr[3] = E3r + W3r; Xi[3] = E3i + W3i;
    Xr[4] = E0r - O0r; Xi[4] = E0i - O0i;
    Xr[5] = E1r - W1r; Xi[5] = E1i - W1i;
    Xr[6] = E2r - W2r; Xi[6] = E2i - W2i;
    Xr[7] = E3r - W3r; Xi[7] = E3i - W3i;
}

// one (u,v) coefficient's contribution — all-scalar args, guaranteed no arrays
__device__ __forceinline__ void coef_term(float R0, float I0, float R1, float I1,
                                          float tval, float wpval, float lum,
                                          float w, bool b1, float beta,
                                          float& sumW, float& sumP) {
    float r0 = R0 + EPSf, i0e = I0 + EPSf;
    float r1 = R1 + EPSf, i1e = I1 + EPSf;
    float a0 = sqrtf(r0 * r0 + i0e * i0e);
    float a1 = sqrtf(r1 * r1 + i1e * i1e);
    float t_l = tval * lum;
    float bb = __powf(a0 + EPSf, w) * __powf(t_l, 1.f - w);
    float f0 = 1.f / (1.f + __expf(bb - t_l));   // softmax weight of t_l
    float s = t_l * f0 + bb * (1.f - f0);
    float term = fabsf((a0 - a1) / s) + EPSf;
    if (!b1) term = __powf(term, beta);
    sumW += term + EPSf;
    // phase: cos(p0 - p1) via dot/norms (imag WITHOUT eps, real WITH eps)
    float dot = r0 * r1 + I0 * I1;
    float nn = fmaxf((r0 * r0 + I0 * I0) * (r1 * r1 + I1 * I1), 1e-36f);
    float cosd = dot * rsqrtf(nn);
    cosd = fminf(fmaxf(cosd * (1.f - 1e-7f), -1.f), 1.f);
    sumP += acosf(cosd) * wpval;
}

// one column (explicit template instantiation -> all indices compile-time)
template <int V>
__device__ __forceinline__ void col_step(const float y0[8][8], const float y1[8][8],
                                         const float* __restrict__ t_tab,
                                         const float* __restrict__ wp_tab,
                                         float avg, float alpha, float w,
                                         bool b1, float beta,
                                         float& lum, float& sumW, float& sumP) {
    float x0r[8], x0i[8], x1r[8], x1i[8];
#pragma unroll
    for (int r = 0; r < 8; r++) {
        if constexpr (V == 0) {
            x0r[r] = y0[r][0]; x0i[r] = 0.f;
            x1r[r] = y1[r][0]; x1i[r] = 0.f;
        } else if constexpr (V == 4) {
            x0r[r] = y0[r][7]; x0i[r] = 0.f;
            x1r[r] = y1[r][7]; x1i[r] = 0.f;
        } else {
            x0r[r] = y0[r][2 * V - 1]; x0i[r] = y0[r][2 * V];
            x1r[r] = y1[r][2 * V - 1]; x1i[r] = y1[r][2 * V];
        }
    }
    float X0r[8], X0i[8], X1r[8], X1i[8];
    cfft8(x0r, x0i, X0r, X0i);
    cfft8(x1r, x1i, X1r, X1i);

    if constexpr (V == 0) {
        float rr = X0r[0] + EPSf, ii = X0i[0] + EPSf;
        float amp00 = sqrtf(rr * rr + ii * ii);
        lum = __powf((amp00 + EPSf) / (avg + EPSf), alpha);
    }

    coef_term(X0r[0], X0i[0], X1r[0], X1i[0], t_tab[0 * 5 + V], wp_tab[0 * 5 + V], lum, w, b1, beta, sumW, sumP);
    coef_term(X0r[1], X0i[1], X1r[1], X1i[1], t_tab[1 * 5 + V], wp_tab[1 * 5 + V], lum, w, b1, beta, sumW, sumP);
    coef_term(X0r[2], X0i[2], X1r[2], X1i[2], t_tab[2 * 5 + V], wp_tab[2 * 5 + V], lum, w, b1, beta, sumW, sumP);
    coef_term(X0r[3], X0i[3], X1r[3], X1i[3], t_tab[3 * 5 + V], wp_tab[3 * 5 + V], lum, w, b1, beta, sumW, sumP);
    coef_term(X0r[4], X0i[4], X1r[4], X1i[4], t_tab[4 * 5 + V], wp_tab[4 * 5 + V], lum, w, b1, beta, sumW, sumP);
    coef_term(X0r[5], X0i[5], X1r[5], X1i[5], t_tab[5 * 5 + V], wp_tab[5 * 5 + V], lum, w, b1, beta, sumW, sumP);
    coef_term(X0r[6], X0i[6], X1r[6], X1i[6], t_tab[6 * 5 + V], wp_tab[6 * 5 + V], lum, w, b1, beta, sumW, sumP);
    coef_term(X0r[7], X0i[7], X1r[7], X1i[7], t_tab[7 * 5 + V], wp_tab[7 * 5 + V], lum, w, b1, beta, sumW, sumP);
}

// ---------------- kernel C: main fused compute --------------------------------
__global__ __launch_bounds__(WG, 2) void kC(const float* __restrict__ tgt,
                                            const float* __restrict__ inp,
                                            const float* __restrict__ t_tild,
                                            const float* __restrict__ alphaP,
                                            const float* __restrict__ wtP,
                                            const float* __restrict__ betaP,
                                            const float* __restrict__ wptP,
                                            const float* __restrict__ avgP,
                                            float* __restrict__ partW,
                                            float* __restrict__ partP) {
    __shared__ float t_tab[40], wp_tab[40];
    if (threadIdx.x < 40) {
        t_tab[threadIdx.x] = __expf(t_tild[threadIdx.x]);
        wp_tab[threadIdx.x] = __expf(wptP[threadIdx.x]);
    }
    __syncthreads();
    float alpha = alphaP[0];
    float w = 1.f / (1.f + __expf(-wtP[0]));
    float beta = betaP[0];
    float avg = avgP[0];
    bool b1 = (beta == 1.0f);

    int gid = blockIdx.x * WG + threadIdx.x;
    int n = gid >> 12, k = gid & 4095;
    int bi = k >> 6, bj = k & 63;
    size_t off = (size_t)n * (IMG_H * IMG_W) + (size_t)(bi * 8) * IMG_W + bj * 8;

    // row FFTs, compact state: 64 floats per image
    float y0[8][8], y1[8][8];
    const float* p0 = tgt + off;
    const float* p1 = inp + off;
#pragma unroll
    for (int r = 0; r < 8; r++) {
        float4 a = *(const float4*)(p0 + (size_t)r * IMG_W);
        float4 b = *(const float4*)(p0 + (size_t)r * IMG_W + 4);
        rowfft8(a, b, y0[r]);
    }
#pragma unroll
    for (int r = 0; r < 8; r++) {
        float4 a = *(const float4*)(p1 + (size_t)r * IMG_W);
        float4 b = *(const float4*)(p1 + (size_t)r * IMG_W + 4);
        rowfft8(a, b, y1[r]);
    }

    float sumW = 0.f, sumP = 0.f;
    float lum = 0.f;
    col_step<0>(y0, y1, t_tab, wp_tab, avg, alpha, w, b1, beta, lum, sumW, sumP);
    col_step<1>(y0, y1, t_tab, wp_tab, avg, alpha, w, b1, beta, lum, sumW, sumP);
    col_step<2>(y0, y1, t_tab, wp_tab, avg, alpha, w, b1, beta, lum, sumW, sumP);
    col_step<3>(y0, y1, t_tab, wp_tab, avg, alpha, w, b1, beta, lum, sumW, sumP);
    col_step<4>(y0, y1, t_tab, wp_tab, avg, alpha, w, b1, beta, lum, sumW, sumP);

    float wW = wave_red(sumW);
    float wP = wave_red(sumP);
    __shared__ float redW[4], redP[4];
    if ((threadIdx.x & 63) == 0) { redW[threadIdx.x >> 6] = wW; redP[threadIdx.x >> 6] = wP; }
    __syncthreads();
    if (threadIdx.x == 0) {
        partW[blockIdx.x] = (redW[0] + redW[1]) + (redW[2] + redW[3]);
        partP[blockIdx.x] = (redP[0] + redP[1]) + (redP[2] + redP[3]);
    }
}

// ---------------- kernel D: per-image final ----------------------------------
__global__ __launch_bounds__(64) void kD(const float* __restrict__ partW,
                                         const float* __restrict__ partP,
                                         const float* __restrict__ betaP,
                                         float* __restrict__ out) {
    int n = threadIdx.x;
    float sW = 0.f, sP = 0.f;
#pragma unroll
    for (int c = 0; c < CHUNKS; c++) {
        sW += partW[n * CHUNKS + c];
        sP += partP[n * CHUNKS + c];
    }
    float beta = betaP[0];
    float wat = (beta == 1.0f) ? sW : __powf(sW, 1.0f / beta);
    out[n] = wat + sP;
}

extern "C" void kernel_launch(void* const* d_in, const int* in_sizes, int n_in,
                              void* d_out, int out_size, void* d_ws, size_t ws_size,
                              hipStream_t stream) {
    const float* inp    = (const float*)d_in[0];
    const float* tgt    = (const float*)d_in[1];
    const float* t_tild = (const float*)d_in[2];
    const float* alphaP = (const float*)d_in[3];
    const float* wtP    = (const float*)d_in[4];
    const float* betaP  = (const float*)d_in[5];
    const float* wptP   = (const float*)d_in[6];
    float* out = (float*)d_out;
    float* ws = (float*)d_ws;
    float* partA = ws;           // [1024]
    float* avgV  = ws + 1024;    // [1]
    float* partW = ws + 1056;    // [1024]
    float* partP = ws + 2080;    // [1024]

    hipLaunchKernelGGL(kA, dim3(NWG), dim3(WG), 0, stream, tgt, partA);
    hipLaunchKernelGGL(kB, dim3(1), dim3(1024), 0, stream, partA, avgV);
    hipLaunchKernelGGL(kC, dim3(NWG), dim3(WG), 0, stream, tgt, inp, t_tild,
                       alphaP, wtP, betaP, wptP, avgV, partW, partP);
    hipLaunchKernelGGL(kD, dim3(1), dim3(64), 0, stream, partW, partP, betaP, out);
}

// Round 4
// 253.857 us; speedup vs baseline: 1.0780x; 1.0780x over previous
//
#include <hip/hip_runtime.h>
#include <math.h>

#define EPSf 1e-10f
#define IMG_N 64
#define IMG_H 512
#define IMG_W 512
#define KBLK 4096                  // 64x64 blocks per image
#define TOTAL_BLK (IMG_N * KBLK)   // 262144
#define WG 256
#define NWG (TOTAL_BLK / WG)       // 1024
#define CHUNKS 16                  // workgroups per image in kC

#define KCc 0.70710678118654752440f
#define SCc (1.0f / 64.0f)

__device__ __forceinline__ float wave_red(float v) {
#pragma unroll
    for (int o = 32; o > 0; o >>= 1) v += __shfl_down(v, o, 64);
    return v;
}

// ---------------- kernel A: per-block DC amplitude of target, partial sums ----
__global__ __launch_bounds__(WG) void kA(const float* __restrict__ tgt,
                                         float* __restrict__ partA) {
    int gid = blockIdx.x * WG + threadIdx.x;
    int n = gid >> 12;
    int k = gid & 4095;
    int bi = k >> 6, bj = k & 63;
    const float* p = tgt + (size_t)n * (IMG_H * IMG_W) + (size_t)(bi * 8) * IMG_W + bj * 8;
    float s = 0.f;
#pragma unroll
    for (int r = 0; r < 8; r++) {
        float4 a = *(const float4*)(p + (size_t)r * IMG_W);
        float4 b = *(const float4*)(p + (size_t)r * IMG_W + 4);
        s += ((a.x + a.y) + (a.z + a.w)) + ((b.x + b.y) + (b.z + b.w));
    }
    float dc = s * (1.0f / 64.0f);                 // rfft2 DC / b^2
    float amp = sqrtf((dc + EPSf) * (dc + EPSf) + EPSf * EPSf);
    float wv = wave_red(amp);
    __shared__ float red[4];
    if ((threadIdx.x & 63) == 0) red[threadIdx.x >> 6] = wv;
    __syncthreads();
    if (threadIdx.x == 0) partA[blockIdx.x] = (red[0] + red[1]) + (red[2] + red[3]);
}

// ---------------- kernel B: reduce 1024 partials -> avg_lum -------------------
__global__ __launch_bounds__(1024) void kB(const float* __restrict__ partA,
                                           float* __restrict__ avgOut) {
    float v = partA[threadIdx.x];
    float wv = wave_red(v);
    __shared__ float red[16];
    if ((threadIdx.x & 63) == 0) red[threadIdx.x >> 6] = wv;
    __syncthreads();
    if (threadIdx.x == 0) {
        float s = 0.f;
#pragma unroll
        for (int i = 0; i < 16; i++) s += red[i];
        avgOut[0] = s * (1.0f / (float)TOTAL_BLK);
    }
}

// row real FFT-8 -> 8 NAMED scalars [c0, c1r, c1i, c2r, c2i, c3r, c3i, c4], /64
#define ROWFFT(A, B, P) do { \
    float s02 = (A).x + (B).x, d02 = (A).x - (B).x; \
    float s26 = (A).z + (B).z, d26 = (A).z - (B).z; \
    float s13 = (A).y + (B).y, d13 = (A).y - (B).y; \
    float s37 = (A).w + (B).w, d37 = (A).w - (B).w; \
    float e0 = s02 + s26, e2 = s02 - s26; \
    float o0 = s13 + s37, o2 = s13 - s37; \
    float cp = KCc * (d13 - d37), cm = KCc * (d13 + d37); \
    P##_0 = SCc * (e0 + o0);  P##_1 = SCc * (d02 + cp); \
    P##_2 = SCc * (-d26 - cm); P##_3 = SCc * e2; \
    P##_4 = SCc * (-o2);      P##_5 = SCc * (d02 - cp); \
    P##_6 = SCc * (d26 - cm); P##_7 = SCc * (e0 - o0); \
} while (0)

#define DECL8(P) float P##_0, P##_1, P##_2, P##_3, P##_4, P##_5, P##_6, P##_7

#define LOADROW(ptr, r, P) do { \
    float4 A = *(const float4*)((ptr) + (size_t)(r) * IMG_W); \
    float4 B = *(const float4*)((ptr) + (size_t)(r) * IMG_W + 4); \
    ROWFFT(A, B, P); \
} while (0)

// complex FFT-8 on 16 scalar inputs -> 16 NAMED scalar outputs PFX0r..PFX7i
#define CFFT8M(PFX, x0r,x0i,x1r,x1i,x2r,x2i,x3r,x3i,x4r,x4i,x5r,x5i,x6r,x6i,x7r,x7i) \
    float PFX##0r, PFX##0i, PFX##1r, PFX##1i, PFX##2r, PFX##2i, PFX##3r, PFX##3i, \
          PFX##4r, PFX##4i, PFX##5r, PFX##5i, PFX##6r, PFX##6i, PFX##7r, PFX##7i; \
    { \
        float t0r = (x0r) + (x4r), t0i = (x0i) + (x4i); \
        float t1r = (x0r) - (x4r), t1i = (x0i) - (x4i); \
        float t2r = (x2r) + (x6r), t2i = (x2i) + (x6i); \
        float t3r = (x2r) - (x6r), t3i = (x2i) - (x6i); \
        float E0r = t0r + t2r, E0i = t0i + t2i; \
        float E2r = t0r - t2r, E2i = t0i - t2i; \
        float E1r = t1r + t3i, E1i = t1i - t3r; \
        float E3r = t1r - t3i, E3i = t1i + t3r; \
        float u0r = (x1r) + (x5r), u0i = (x1i) + (x5i); \
        float u1r = (x1r) - (x5r), u1i = (x1i) - (x5i); \
        float u2r = (x3r) + (x7r), u2i = (x3i) + (x7i); \
        float u3r = (x3r) - (x7r), u3i = (x3i) - (x7i); \
        float O0r = u0r + u2r, O0i = u0i + u2i; \
        float O2r = u0r - u2r, O2i = u0i - u2i; \
        float O1r = u1r + u3i, O1i = u1i - u3r; \
        float O3r = u1r - u3i, O3i = u1i + u3r; \
        float W1r = KCc * (O1r + O1i), W1i = KCc * (O1i - O1r); \
        float W2r = O2i,               W2i = -O2r; \
        float W3r = KCc * (O3i - O3r), W3i = -KCc * (O3r + O3i); \
        PFX##0r = E0r + O0r; PFX##0i = E0i + O0i; \
        PFX##1r = E1r + W1r; PFX##1i = E1i + W1i; \
        PFX##2r = E2r + W2r; PFX##2i = E2i + W2i; \
        PFX##3r = E3r + W3r; PFX##3i = E3i + W3i; \
        PFX##4r = E0r - O0r; PFX##4i = E0i - O0i; \
        PFX##5r = E1r - W1r; PFX##5i = E1i - W1i; \
        PFX##6r = E2r - W2r; PFX##6i = E2i - W2i; \
        PFX##7r = E3r - W3r; PFX##7i = E3i - W3i; \
    }

// one (u,v) coefficient's contribution — all-scalar args
__device__ __forceinline__ void coef_term(float R0, float I0, float R1, float I1,
                                          float tval, float wpval, float lum,
                                          float w, bool b1, float beta,
                                          float& sumW, float& sumP) {
    float r0 = R0 + EPSf, i0e = I0 + EPSf;
    float r1 = R1 + EPSf, i1e = I1 + EPSf;
    float a0 = sqrtf(r0 * r0 + i0e * i0e);
    float a1 = sqrtf(r1 * r1 + i1e * i1e);
    float t_l = tval * lum;
    float bb = __powf(a0 + EPSf, w) * __powf(t_l, 1.f - w);
    float f0 = 1.f / (1.f + __expf(bb - t_l));   // softmax weight of t_l
    float s = t_l * f0 + bb * (1.f - f0);
    float term = fabsf((a0 - a1) / s) + EPSf;
    if (!b1) term = __powf(term, beta);
    sumW += term + EPSf;
    // phase: cos(p0 - p1) via dot/norms (imag WITHOUT eps, real WITH eps)
    float dot = r0 * r1 + I0 * I1;
    float nn = fmaxf((r0 * r0 + I0 * I0) * (r1 * r1 + I1 * I1), 1e-36f);
    float cosd = dot * rsqrtf(nn);
    cosd = fminf(fmaxf(cosd * (1.f - 1e-7f), -1.f), 1.f);
    sumP += acosf(cosd) * wpval;
}

#define COEFS(V) \
    coef_term(X00r, X00i, X10r, X10i, t_tab[0*5+(V)], wp_tab[0*5+(V)], lum, w, b1, beta, sumW, sumP); \
    coef_term(X01r, X01i, X11r, X11i, t_tab[1*5+(V)], wp_tab[1*5+(V)], lum, w, b1, beta, sumW, sumP); \
    coef_term(X02r, X02i, X12r, X12i, t_tab[2*5+(V)], wp_tab[2*5+(V)], lum, w, b1, beta, sumW, sumP); \
    coef_term(X03r, X03i, X13r, X13i, t_tab[3*5+(V)], wp_tab[3*5+(V)], lum, w, b1, beta, sumW, sumP); \
    coef_term(X04r, X04i, X14r, X14i, t_tab[4*5+(V)], wp_tab[4*5+(V)], lum, w, b1, beta, sumW, sumP); \
    coef_term(X05r, X05i, X15r, X15i, t_tab[5*5+(V)], wp_tab[5*5+(V)], lum, w, b1, beta, sumW, sumP); \
    coef_term(X06r, X06i, X16r, X16i, t_tab[6*5+(V)], wp_tab[6*5+(V)], lum, w, b1, beta, sumW, sumP); \
    coef_term(X07r, X07i, X17r, X17i, t_tab[7*5+(V)], wp_tab[7*5+(V)], lum, w, b1, beta, sumW, sumP);

// ---------------- kernel C: main fused compute --------------------------------
__global__ __launch_bounds__(WG, 2) void kC(const float* __restrict__ tgt,
                                            const float* __restrict__ inp,
                                            const float* __restrict__ t_tild,
                                            const float* __restrict__ alphaP,
                                            const float* __restrict__ wtP,
                                            const float* __restrict__ betaP,
                                            const float* __restrict__ wptP,
                                            const float* __restrict__ avgP,
                                            float* __restrict__ partW,
                                            float* __restrict__ partP) {
    __shared__ float t_tab[40], wp_tab[40];
    if (threadIdx.x < 40) {
        t_tab[threadIdx.x] = __expf(t_tild[threadIdx.x]);
        wp_tab[threadIdx.x] = __expf(wptP[threadIdx.x]);
    }
    __syncthreads();
    float alpha = alphaP[0];
    float w = 1.f / (1.f + __expf(-wtP[0]));
    float beta = betaP[0];
    float avg = avgP[0];
    bool b1 = (beta == 1.0f);

    int gid = blockIdx.x * WG + threadIdx.x;
    int n = gid >> 12, k = gid & 4095;
    int bi = k >> 6, bj = k & 63;
    size_t off = (size_t)n * (IMG_H * IMG_W) + (size_t)(bi * 8) * IMG_W + bj * 8;
    const float* p0 = tgt + off;
    const float* p1 = inp + off;

    // row FFT state: 128 individually named scalars (no arrays -> no scratch)
    DECL8(ta0); DECL8(ta1); DECL8(ta2); DECL8(ta3);
    DECL8(ta4); DECL8(ta5); DECL8(ta6); DECL8(ta7);
    DECL8(tb0); DECL8(tb1); DECL8(tb2); DECL8(tb3);
    DECL8(tb4); DECL8(tb5); DECL8(tb6); DECL8(tb7);

    LOADROW(p0, 0, ta0); LOADROW(p0, 1, ta1); LOADROW(p0, 2, ta2); LOADROW(p0, 3, ta3);
    LOADROW(p0, 4, ta4); LOADROW(p0, 5, ta5); LOADROW(p0, 6, ta6); LOADROW(p0, 7, ta7);
    LOADROW(p1, 0, tb0); LOADROW(p1, 1, tb1); LOADROW(p1, 2, tb2); LOADROW(p1, 3, tb3);
    LOADROW(p1, 4, tb4); LOADROW(p1, 5, tb5); LOADROW(p1, 6, tb6); LOADROW(p1, 7, tb7);

    float sumW = 0.f, sumP = 0.f;
    float lum = 0.f;

    { // v = 0 : real column, component 0
        CFFT8M(X0, ta0_0, 0.f, ta1_0, 0.f, ta2_0, 0.f, ta3_0, 0.f,
                   ta4_0, 0.f, ta5_0, 0.f, ta6_0, 0.f, ta7_0, 0.f)
        CFFT8M(X1, tb0_0, 0.f, tb1_0, 0.f, tb2_0, 0.f, tb3_0, 0.f,
                   tb4_0, 0.f, tb5_0, 0.f, tb6_0, 0.f, tb7_0, 0.f)
        float rr = X00r + EPSf, ii = X00i + EPSf;
        float amp00 = sqrtf(rr * rr + ii * ii);
        lum = __powf((amp00 + EPSf) / (avg + EPSf), alpha);
        COEFS(0)
    }
    { // v = 1 : components 1 (re), 2 (im)
        CFFT8M(X0, ta0_1, ta0_2, ta1_1, ta1_2, ta2_1, ta2_2, ta3_1, ta3_2,
                   ta4_1, ta4_2, ta5_1, ta5_2, ta6_1, ta6_2, ta7_1, ta7_2)
        CFFT8M(X1, tb0_1, tb0_2, tb1_1, tb1_2, tb2_1, tb2_2, tb3_1, tb3_2,
                   tb4_1, tb4_2, tb5_1, tb5_2, tb6_1, tb6_2, tb7_1, tb7_2)
        COEFS(1)
    }
    { // v = 2 : components 3, 4
        CFFT8M(X0, ta0_3, ta0_4, ta1_3, ta1_4, ta2_3, ta2_4, ta3_3, ta3_4,
                   ta4_3, ta4_4, ta5_3, ta5_4, ta6_3, ta6_4, ta7_3, ta7_4)
        CFFT8M(X1, tb0_3, tb0_4, tb1_3, tb1_4, tb2_3, tb2_4, tb3_3, tb3_4,
                   tb4_3, tb4_4, tb5_3, tb5_4, tb6_3, tb6_4, tb7_3, tb7_4)
        COEFS(2)
    }
    { // v = 3 : components 5, 6
        CFFT8M(X0, ta0_5, ta0_6, ta1_5, ta1_6, ta2_5, ta2_6, ta3_5, ta3_6,
                   ta4_5, ta4_6, ta5_5, ta5_6, ta6_5, ta6_6, ta7_5, ta7_6)
        CFFT8M(X1, tb0_5, tb0_6, tb1_5, tb1_6, tb2_5, tb2_6, tb3_5, tb3_6,
                   tb4_5, tb4_6, tb5_5, tb5_6, tb6_5, tb6_6, tb7_5, tb7_6)
        COEFS(3)
    }
    { // v = 4 : real column, component 7
        CFFT8M(X0, ta0_7, 0.f, ta1_7, 0.f, ta2_7, 0.f, ta3_7, 0.f,
                   ta4_7, 0.f, ta5_7, 0.f, ta6_7, 0.f, ta7_7, 0.f)
        CFFT8M(X1, tb0_7, 0.f, tb1_7, 0.f, tb2_7, 0.f, tb3_7, 0.f,
                   tb4_7, 0.f, tb5_7, 0.f, tb6_7, 0.f, tb7_7, 0.f)
        COEFS(4)
    }

    float wW = wave_red(sumW);
    float wP = wave_red(sumP);
    __shared__ float redW[4], redP[4];
    if ((threadIdx.x & 63) == 0) { redW[threadIdx.x >> 6] = wW; redP[threadIdx.x >> 6] = wP; }
    __syncthreads();
    if (threadIdx.x == 0) {
        partW[blockIdx.x] = (redW[0] + redW[1]) + (redW[2] + redW[3]);
        partP[blockIdx.x] = (redP[0] + redP[1]) + (redP[2] + redP[3]);
    }
}

// ---------------- kernel D: per-image final ----------------------------------
__global__ __launch_bounds__(64) void kD(const float* __restrict__ partW,
                                         const float* __restrict__ partP,
                                         const float* __restrict__ betaP,
                                         float* __restrict__ out) {
    int n = threadIdx.x;
    float sW = 0.f, sP = 0.f;
#pragma unroll
    for (int c = 0; c < CHUNKS; c++) {
        sW += partW[n * CHUNKS + c];
        sP += partP[n * CHUNKS + c];
    }
    float beta = betaP[0];
    float wat = (beta == 1.0f) ? sW : __powf(sW, 1.0f / beta);
    out[n] = wat + sP;
}

extern "C" void kernel_launch(void* const* d_in, const int* in_sizes, int n_in,
                              void* d_out, int out_size, void* d_ws, size_t ws_size,
                              hipStream_t stream) {
    const float* inp    = (const float*)d_in[0];
    const float* tgt    = (const float*)d_in[1];
    const float* t_tild = (const float*)d_in[2];
    const float* alphaP = (const float*)d_in[3];
    const float* wtP    = (const float*)d_in[4];
    const float* betaP  = (const float*)d_in[5];
    const float* wptP   = (const float*)d_in[6];
    float* out = (float*)d_out;
    float* ws = (float*)d_ws;
    float* partA = ws;           // [1024]
    float* avgV  = ws + 1024;    // [1]
    float* partW = ws + 1056;    // [1024]
    float* partP = ws + 2080;    // [1024]

    hipLaunchKernelGGL(kA, dim3(NWG), dim3(WG), 0, stream, tgt, partA);
    hipLaunchKernelGGL(kB, dim3(1), dim3(1024), 0, stream, partA, avgV);
    hipLaunchKernelGGL(kC, dim3(NWG), dim3(WG), 0, stream, tgt, inp, t_tild,
                       alphaP, wtP, betaP, wptP, avgV, partW, partP);
    hipLaunchKernelGGL(kD, dim3(1), dim3(64), 0, stream, partW, partP, betaP, out);
}

// Round 5
// 158.087 us; speedup vs baseline: 1.7310x; 1.6058x over previous
//
#include <hip/hip_runtime.h>
#include <math.h>

#define EPSf 1e-10f
#define IMG_N 64
#define IMG_H 512
#define IMG_W 512
#define KBLK 4096                  // 64x64 blocks per image
#define TOTAL_BLK (IMG_N * KBLK)   // 262144
#define WG 256
#define NWG (TOTAL_BLK / WG)       // 1024 (kA)
#define NWG2 (TOTAL_BLK * 2 / WG)  // 2048 (kC: 2 lanes per block-pair)
#define CHUNKS 32                  // kC workgroups per image (2048/64)

#define KCc 0.70710678118654752440f
#define SCc (1.0f / 64.0f)

__device__ __forceinline__ float wave_red(float v) {
#pragma unroll
    for (int o = 32; o > 0; o >>= 1) v += __shfl_down(v, o, 64);
    return v;
}

// ---------------- kernel A: per-block DC amplitude of target, partial sums ----
__global__ __launch_bounds__(WG) void kA(const float* __restrict__ tgt,
                                         float* __restrict__ partA) {
    int gid = blockIdx.x * WG + threadIdx.x;
    int n = gid >> 12;
    int k = gid & 4095;
    int bi = k >> 6, bj = k & 63;
    const float* p = tgt + (size_t)n * (IMG_H * IMG_W) + (size_t)(bi * 8) * IMG_W + bj * 8;
    float s = 0.f;
#pragma unroll
    for (int r = 0; r < 8; r++) {
        float4 a = *(const float4*)(p + (size_t)r * IMG_W);
        float4 b = *(const float4*)(p + (size_t)r * IMG_W + 4);
        s += ((a.x + a.y) + (a.z + a.w)) + ((b.x + b.y) + (b.z + b.w));
    }
    float dc = s * (1.0f / 64.0f);                 // rfft2 DC / b^2
    float amp = sqrtf((dc + EPSf) * (dc + EPSf) + EPSf * EPSf);
    float wv = wave_red(amp);
    __shared__ float red[4];
    if ((threadIdx.x & 63) == 0) red[threadIdx.x >> 6] = wv;
    __syncthreads();
    if (threadIdx.x == 0) partA[blockIdx.x] = (red[0] + red[1]) + (red[2] + red[3]);
}

// ---------------- kernel B: reduce 1024 partials -> avg_lum -------------------
__global__ __launch_bounds__(1024) void kB(const float* __restrict__ partA,
                                           float* __restrict__ avgOut) {
    float v = partA[threadIdx.x];
    float wv = wave_red(v);
    __shared__ float red[16];
    if ((threadIdx.x & 63) == 0) red[threadIdx.x >> 6] = wv;
    __syncthreads();
    if (threadIdx.x == 0) {
        float s = 0.f;
#pragma unroll
        for (int i = 0; i < 16; i++) s += red[i];
        avgOut[0] = s * (1.0f / (float)TOTAL_BLK);
    }
}

// row real FFT-8 -> 8 NAMED scalars [c0, c1r, c1i, c2r, c2i, c3r, c3i, c4], /64
#define ROWFFT(A, B, P) do { \
    float s02 = (A).x + (B).x, d02 = (A).x - (B).x; \
    float s26 = (A).z + (B).z, d26 = (A).z - (B).z; \
    float s13 = (A).y + (B).y, d13 = (A).y - (B).y; \
    float s37 = (A).w + (B).w, d37 = (A).w - (B).w; \
    float e0 = s02 + s26, e2 = s02 - s26; \
    float o0 = s13 + s37, o2 = s13 - s37; \
    float cp = KCc * (d13 - d37), cm = KCc * (d13 + d37); \
    P##_0 = SCc * (e0 + o0);  P##_1 = SCc * (d02 + cp); \
    P##_2 = SCc * (-d26 - cm); P##_3 = SCc * e2; \
    P##_4 = SCc * (-o2);      P##_5 = SCc * (d02 - cp); \
    P##_6 = SCc * (d26 - cm); P##_7 = SCc * (e0 - o0); \
} while (0)

#define DECL8(P) float P##_0, P##_1, P##_2, P##_3, P##_4, P##_5, P##_6, P##_7

#define LOADROW(ptr, r, P) do { \
    float4 A = *(const float4*)((ptr) + (size_t)(r) * IMG_W); \
    float4 B = *(const float4*)((ptr) + (size_t)(r) * IMG_W + 4); \
    ROWFFT(A, B, P); \
} while (0)

// complex FFT-8 on 16 scalar inputs -> 16 NAMED scalar outputs PFX0r..PFX7i
#define CFFT8M(PFX, x0r,x0i,x1r,x1i,x2r,x2i,x3r,x3i,x4r,x4i,x5r,x5i,x6r,x6i,x7r,x7i) \
    float PFX##0r, PFX##0i, PFX##1r, PFX##1i, PFX##2r, PFX##2i, PFX##3r, PFX##3i, \
          PFX##4r, PFX##4i, PFX##5r, PFX##5i, PFX##6r, PFX##6i, PFX##7r, PFX##7i; \
    { \
        float t0r = (x0r) + (x4r), t0i = (x0i) + (x4i); \
        float t1r = (x0r) - (x4r), t1i = (x0i) - (x4i); \
        float t2r = (x2r) + (x6r), t2i = (x2i) + (x6i); \
        float t3r = (x2r) - (x6r), t3i = (x2i) - (x6i); \
        float E0r = t0r + t2r, E0i = t0i + t2i; \
        float E2r = t0r - t2r, E2i = t0i - t2i; \
        float E1r = t1r + t3i, E1i = t1i - t3r; \
        float E3r = t1r - t3i, E3i = t1i + t3r; \
        float u0r = (x1r) + (x5r), u0i = (x1i) + (x5i); \
        float u1r = (x1r) - (x5r), u1i = (x1i) - (x5i); \
        float u2r = (x3r) + (x7r), u2i = (x3i) + (x7i); \
        float u3r = (x3r) - (x7r), u3i = (x3i) - (x7i); \
        float O0r = u0r + u2r, O0i = u0i + u2i; \
        float O2r = u0r - u2r, O2i = u0i - u2i; \
        float O1r = u1r + u3i, O1i = u1i - u3r; \
        float O3r = u1r - u3i, O3i = u1i + u3r; \
        float W1r = KCc * (O1r + O1i), W1i = KCc * (O1i - O1r); \
        float W2r = O2i,               W2i = -O2r; \
        float W3r = KCc * (O3i - O3r), W3i = -KCc * (O3r + O3i); \
        PFX##0r = E0r + O0r; PFX##0i = E0i + O0i; \
        PFX##1r = E1r + W1r; PFX##1i = E1i + W1i; \
        PFX##2r = E2r + W2r; PFX##2i = E2i + W2i; \
        PFX##3r = E3r + W3r; PFX##3i = E3i + W3i; \
        PFX##4r = E0r - O0r; PFX##4i = E0i - O0i; \
        PFX##5r = E1r - W1r; PFX##5i = E1i - W1i; \
        PFX##6r = E2r - W2r; PFX##6i = E2i - W2i; \
        PFX##7r = E3r - W3r; PFX##7i = E3i - W3i; \
    }

// exchange own 16-spectrum with the partner lane (lane^1)
#define EXCH() \
    float P0r = __shfl_xor(X0r, 1, 64), P0i = __shfl_xor(X0i, 1, 64); \
    float P1r = __shfl_xor(X1r, 1, 64), P1i = __shfl_xor(X1i, 1, 64); \
    float P2r = __shfl_xor(X2r, 1, 64), P2i = __shfl_xor(X2i, 1, 64); \
    float P3r = __shfl_xor(X3r, 1, 64), P3i = __shfl_xor(X3i, 1, 64); \
    float P4r = __shfl_xor(X4r, 1, 64), P4i = __shfl_xor(X4i, 1, 64); \
    float P5r = __shfl_xor(X5r, 1, 64), P5i = __shfl_xor(X5i, 1, 64); \
    float P6r = __shfl_xor(X6r, 1, 64), P6i = __shfl_xor(X6i, 1, 64); \
    float P7r = __shfl_xor(X7r, 1, 64), P7i = __shfl_xor(X7i, 1, 64);

// one (u,v) coefficient's contribution — all-scalar args
__device__ __forceinline__ void coef_term(float R0, float I0, float R1, float I1,
                                          float tval, float wpval, float lum,
                                          float w, bool b1, float beta,
                                          float& sumW, float& sumP) {
    float r0 = R0 + EPSf, i0e = I0 + EPSf;
    float r1 = R1 + EPSf, i1e = I1 + EPSf;
    float a0 = sqrtf(r0 * r0 + i0e * i0e);
    float a1 = sqrtf(r1 * r1 + i1e * i1e);
    float t_l = tval * lum;
    float bb = __powf(a0 + EPSf, w) * __powf(t_l, 1.f - w);
    float f0 = 1.f / (1.f + __expf(bb - t_l));   // softmax weight of t_l
    float s = t_l * f0 + bb * (1.f - f0);
    float term = fabsf((a0 - a1) / s) + EPSf;
    if (!b1) term = __powf(term, beta);
    sumW += term + EPSf;
    // phase: cos(p0 - p1) via dot/norms (imag WITHOUT eps, real WITH eps)
    float dot = r0 * r1 + I0 * I1;
    float nn = fmaxf((r0 * r0 + I0 * I0) * (r1 * r1 + I1 * I1), 1e-36f);
    float cosd = dot * rsqrtf(nn);
    cosd = fminf(fmaxf(cosd * (1.f - 1e-7f), -1.f), 1.f);
    sumP += acosf(cosd) * wpval;
}

// 4 coefficient slots per lane. even lane (img=0): u = slot (target=own X, input=partner P)
// odd lane (img=1): u = slot+4 (target=partner P, input=own X). ternaries -> v_cndmask.
#define COEFS2(V) do { \
    coef_term(img ? P4r : X0r, img ? P4i : X0i, img ? X4r : P0r, img ? X4i : P0i, \
              t_tab[20*img + 0*5 + (V)], wp_tab[20*img + 0*5 + (V)], lum, w, b1, beta, sumW, sumP); \
    coef_term(img ? P5r : X1r, img ? P5i : X1i, img ? X5r : P1r, img ? X5i : P1i, \
              t_tab[20*img + 1*5 + (V)], wp_tab[20*img + 1*5 + (V)], lum, w, b1, beta, sumW, sumP); \
    coef_term(img ? P6r : X2r, img ? P6i : X2i, img ? X6r : P2r, img ? X6i : P2i, \
              t_tab[20*img + 2*5 + (V)], wp_tab[20*img + 2*5 + (V)], lum, w, b1, beta, sumW, sumP); \
    coef_term(img ? P7r : X3r, img ? P7i : X3i, img ? X7r : P3r, img ? X7i : P3i, \
              t_tab[20*img + 3*5 + (V)], wp_tab[20*img + 3*5 + (V)], lum, w, b1, beta, sumW, sumP); \
} while (0)

// ---------------- kernel C: main fused compute (2 lanes per block-pair) -------
__global__ __launch_bounds__(WG, 2) void kC(const float* __restrict__ tgt,
                                            const float* __restrict__ inp,
                                            const float* __restrict__ t_tild,
                                            const float* __restrict__ alphaP,
                                            const float* __restrict__ wtP,
                                            const float* __restrict__ betaP,
                                            const float* __restrict__ wptP,
                                            const float* __restrict__ avgP,
                                            float* __restrict__ partW,
                                            float* __restrict__ partP) {
    __shared__ float t_tab[40], wp_tab[40];
    if (threadIdx.x < 40) {
        t_tab[threadIdx.x] = __expf(t_tild[threadIdx.x]);
        wp_tab[threadIdx.x] = __expf(wptP[threadIdx.x]);
    }
    __syncthreads();
    float alpha = alphaP[0];
    float w = 1.f / (1.f + __expf(-wtP[0]));
    float beta = betaP[0];
    float avg = avgP[0];
    bool b1 = (beta == 1.0f);

    int gid = blockIdx.x * WG + threadIdx.x;
    int p = gid >> 1;          // block-pair index
    int img = gid & 1;         // 0 = target, 1 = input  (== lane parity)
    int n = p >> 12, k = p & 4095;
    int bi = k >> 6, bj = k & 63;
    size_t off = (size_t)n * (IMG_H * IMG_W) + (size_t)(bi * 8) * IMG_W + bj * 8;
    const float* src = (img ? inp : tgt) + off;

    // row FFT state for ONE image: 64 named scalars
    DECL8(t0); DECL8(t1); DECL8(t2); DECL8(t3);
    DECL8(t4); DECL8(t5); DECL8(t6); DECL8(t7);
    LOADROW(src, 0, t0); LOADROW(src, 1, t1); LOADROW(src, 2, t2); LOADROW(src, 3, t3);
    LOADROW(src, 4, t4); LOADROW(src, 5, t5); LOADROW(src, 6, t6); LOADROW(src, 7, t7);

    float sumW = 0.f, sumP = 0.f;
    float lum = 0.f;

    { // v = 0 : real column, component 0
        CFFT8M(X, t0_0, 0.f, t1_0, 0.f, t2_0, 0.f, t3_0, 0.f,
                  t4_0, 0.f, t5_0, 0.f, t6_0, 0.f, t7_0, 0.f)
        // lum from TARGET's DC amp (even lane owns it)
        float rr = X0r + EPSf, ii = X0i + EPSf;
        float myamp = sqrtf(rr * rr + ii * ii);
        float oamp = __shfl_xor(myamp, 1, 64);
        float amp00 = img ? oamp : myamp;
        lum = __powf((amp00 + EPSf) / (avg + EPSf), alpha);
        EXCH()
        COEFS2(0);
    }
    { // v = 1 : components 1 (re), 2 (im)
        CFFT8M(X, t0_1, t0_2, t1_1, t1_2, t2_1, t2_2, t3_1, t3_2,
                  t4_1, t4_2, t5_1, t5_2, t6_1, t6_2, t7_1, t7_2)
        EXCH()
        COEFS2(1);
    }
    { // v = 2 : components 3, 4
        CFFT8M(X, t0_3, t0_4, t1_3, t1_4, t2_3, t2_4, t3_3, t3_4,
                  t4_3, t4_4, t5_3, t5_4, t6_3, t6_4, t7_3, t7_4)
        EXCH()
        COEFS2(2);
    }
    { // v = 3 : components 5, 6
        CFFT8M(X, t0_5, t0_6, t1_5, t1_6, t2_5, t2_6, t3_5, t3_6,
                  t4_5, t4_6, t5_5, t5_6, t6_5, t6_6, t7_5, t7_6)
        EXCH()
        COEFS2(3);
    }
    { // v = 4 : real column, component 7
        CFFT8M(X, t0_7, 0.f, t1_7, 0.f, t2_7, 0.f, t3_7, 0.f,
                  t4_7, 0.f, t5_7, 0.f, t6_7, 0.f, t7_7, 0.f)
        EXCH()
        COEFS2(4);
    }

    float wW = wave_red(sumW);
    float wP = wave_red(sumP);
    __shared__ float redW[4], redP[4];
    if ((threadIdx.x & 63) == 0) { redW[threadIdx.x >> 6] = wW; redP[threadIdx.x >> 6] = wP; }
    __syncthreads();
    if (threadIdx.x == 0) {
        partW[blockIdx.x] = (redW[0] + redW[1]) + (redW[2] + redW[3]);
        partP[blockIdx.x] = (redP[0] + redP[1]) + (redP[2] + redP[3]);
    }
}

// ---------------- kernel D: per-image final ----------------------------------
__global__ __launch_bounds__(64) void kD(const float* __restrict__ partW,
                                         const float* __restrict__ partP,
                                         const float* __restrict__ betaP,
                                         float* __restrict__ out) {
    int n = threadIdx.x;
    float sW = 0.f, sP = 0.f;
#pragma unroll
    for (int c = 0; c < CHUNKS; c++) {
        sW += partW[n * CHUNKS + c];
        sP += partP[n * CHUNKS + c];
    }
    float beta = betaP[0];
    float wat = (beta == 1.0f) ? sW : __powf(sW, 1.0f / beta);
    out[n] = wat + sP;
}

extern "C" void kernel_launch(void* const* d_in, const int* in_sizes, int n_in,
                              void* d_out, int out_size, void* d_ws, size_t ws_size,
                              hipStream_t stream) {
    const float* inp    = (const float*)d_in[0];
    const float* tgt    = (const float*)d_in[1];
    const float* t_tild = (const float*)d_in[2];
    const float* alphaP = (const float*)d_in[3];
    const float* wtP    = (const float*)d_in[4];
    const float* betaP  = (const float*)d_in[5];
    const float* wptP   = (const float*)d_in[6];
    float* out = (float*)d_out;
    float* ws = (float*)d_ws;
    float* partA = ws;           // [1024]
    float* avgV  = ws + 1024;    // [1]
    float* partW = ws + 1056;    // [2048]
    float* partP = ws + 3104;    // [2048]

    hipLaunchKernelGGL(kA, dim3(NWG), dim3(WG), 0, stream, tgt, partA);
    hipLaunchKernelGGL(kB, dim3(1), dim3(1024), 0, stream, partA, avgV);
    hipLaunchKernelGGL(kC, dim3(NWG2), dim3(WG), 0, stream, tgt, inp, t_tild,
                       alphaP, wtP, betaP, wptP, avgV, partW, partP);
    hipLaunchKernelGGL(kD, dim3(1), dim3(64), 0, stream, partW, partP, betaP, out);
}

// Round 6
// 60.092 us; speedup vs baseline: 4.5538x; 2.6307x over previous
//
#include <hip/hip_runtime.h>
#include <math.h>

#define EPSf 1e-10f
#define IMG_N 64
#define IMG_H 512
#define IMG_W 512
#define KBLK 4096                  // 64x64 blocks per image
#define TOTAL_BLK (IMG_N * KBLK)   // 262144
#define WG 256
#define NWG (TOTAL_BLK / WG)       // 1024 (kA)
#define NWG2 (TOTAL_BLK * 2 / WG)  // 2048 (kC: 2 lanes per block-pair)
#define CHUNKS 32                  // kC workgroups per image (2048/64)

#define KCc 0.70710678118654752440f
#define SCc (1.0f / 64.0f)
#define LOG2E 1.44269504088896340736f

__device__ __forceinline__ float wave_red(float v) {
#pragma unroll
    for (int o = 32; o > 0; o >>= 1) v += __shfl_down(v, o, 64);
    return v;
}

// ---------------- kernel A: per-block DC amplitude of target, partial sums ----
__global__ __launch_bounds__(WG) void kA(const float* __restrict__ tgt,
                                         float* __restrict__ partA) {
    int gid = blockIdx.x * WG + threadIdx.x;
    int n = gid >> 12;
    int k = gid & 4095;
    int bi = k >> 6, bj = k & 63;
    const float* p = tgt + (size_t)n * (IMG_H * IMG_W) + (size_t)(bi * 8) * IMG_W + bj * 8;
    float s = 0.f;
#pragma unroll
    for (int r = 0; r < 8; r++) {
        float4 a = *(const float4*)(p + (size_t)r * IMG_W);
        float4 b = *(const float4*)(p + (size_t)r * IMG_W + 4);
        s += ((a.x + a.y) + (a.z + a.w)) + ((b.x + b.y) + (b.z + b.w));
    }
    float dc = s * (1.0f / 64.0f);                 // rfft2 DC / b^2
    float amp = sqrtf((dc + EPSf) * (dc + EPSf) + EPSf * EPSf);
    float wv = wave_red(amp);
    __shared__ float red[4];
    if ((threadIdx.x & 63) == 0) red[threadIdx.x >> 6] = wv;
    __syncthreads();
    if (threadIdx.x == 0) partA[blockIdx.x] = (red[0] + red[1]) + (red[2] + red[3]);
}

// ---------------- kernel B: reduce 1024 partials -> avg_lum -------------------
__global__ __launch_bounds__(1024) void kB(const float* __restrict__ partA,
                                           float* __restrict__ avgOut) {
    float v = partA[threadIdx.x];
    float wv = wave_red(v);
    __shared__ float red[16];
    if ((threadIdx.x & 63) == 0) red[threadIdx.x >> 6] = wv;
    __syncthreads();
    if (threadIdx.x == 0) {
        float s = 0.f;
#pragma unroll
        for (int i = 0; i < 16; i++) s += red[i];
        avgOut[0] = s * (1.0f / (float)TOTAL_BLK);
    }
}

// row real FFT-8 -> 8 NAMED scalars [c0, c1r, c1i, c2r, c2i, c3r, c3i, c4], /64
#define ROWFFT(A, B, P) do { \
    float s02 = (A).x + (B).x, d02 = (A).x - (B).x; \
    float s26 = (A).z + (B).z, d26 = (A).z - (B).z; \
    float s13 = (A).y + (B).y, d13 = (A).y - (B).y; \
    float s37 = (A).w + (B).w, d37 = (A).w - (B).w; \
    float e0 = s02 + s26, e2 = s02 - s26; \
    float o0 = s13 + s37, o2 = s13 - s37; \
    float cp = KCc * (d13 - d37), cm = KCc * (d13 + d37); \
    P##_0 = SCc * (e0 + o0);  P##_1 = SCc * (d02 + cp); \
    P##_2 = SCc * (-d26 - cm); P##_3 = SCc * e2; \
    P##_4 = SCc * (-o2);      P##_5 = SCc * (d02 - cp); \
    P##_6 = SCc * (d26 - cm); P##_7 = SCc * (e0 - o0); \
} while (0)

#define DECL8(P) float P##_0, P##_1, P##_2, P##_3, P##_4, P##_5, P##_6, P##_7

#define LOADROW(ptr, r, P) do { \
    float4 A = *(const float4*)((ptr) + (size_t)(r) * IMG_W); \
    float4 B = *(const float4*)((ptr) + (size_t)(r) * IMG_W + 4); \
    ROWFFT(A, B, P); \
} while (0)

// complex FFT-8 on 16 scalar inputs -> 16 NAMED scalar outputs PFX0r..PFX7i
#define CFFT8M(PFX, x0r,x0i,x1r,x1i,x2r,x2i,x3r,x3i,x4r,x4i,x5r,x5i,x6r,x6i,x7r,x7i) \
    float PFX##0r, PFX##0i, PFX##1r, PFX##1i, PFX##2r, PFX##2i, PFX##3r, PFX##3i, \
          PFX##4r, PFX##4i, PFX##5r, PFX##5i, PFX##6r, PFX##6i, PFX##7r, PFX##7i; \
    { \
        float t0r = (x0r) + (x4r), t0i = (x0i) + (x4i); \
        float t1r = (x0r) - (x4r), t1i = (x0i) - (x4i); \
        float t2r = (x2r) + (x6r), t2i = (x2i) + (x6i); \
        float t3r = (x2r) - (x6r), t3i = (x2i) - (x6i); \
        float E0r = t0r + t2r, E0i = t0i + t2i; \
        float E2r = t0r - t2r, E2i = t0i - t2i; \
        float E1r = t1r + t3i, E1i = t1i - t3r; \
        float E3r = t1r - t3i, E3i = t1i + t3r; \
        float u0r = (x1r) + (x5r), u0i = (x1i) + (x5i); \
        float u1r = (x1r) - (x5r), u1i = (x1i) - (x5i); \
        float u2r = (x3r) + (x7r), u2i = (x3i) + (x7i); \
        float u3r = (x3r) - (x7r), u3i = (x3i) - (x7i); \
        float O0r = u0r + u2r, O0i = u0i + u2i; \
        float O2r = u0r - u2r, O2i = u0i - u2i; \
        float O1r = u1r + u3i, O1i = u1i - u3r; \
        float O3r = u1r - u3i, O3i = u1i + u3r; \
        float W1r = KCc * (O1r + O1i), W1i = KCc * (O1i - O1r); \
        float W2r = O2i,               W2i = -O2r; \
        float W3r = KCc * (O3i - O3r), W3i = -KCc * (O3r + O3i); \
        PFX##0r = E0r + O0r; PFX##0i = E0i + O0i; \
        PFX##1r = E1r + W1r; PFX##1i = E1i + W1i; \
        PFX##2r = E2r + W2r; PFX##2i = E2i + W2i; \
        PFX##3r = E3r + W3r; PFX##3i = E3i + W3i; \
        PFX##4r = E0r - O0r; PFX##4i = E0i - O0i; \
        PFX##5r = E1r - W1r; PFX##5i = E1i - W1i; \
        PFX##6r = E2r - W2r; PFX##6i = E2i - W2i; \
        PFX##7r = E3r - W3r; PFX##7i = E3i - W3i; \
    }

// fast acos: Abramowitz-Stegun 4.4.45 (3-term), max err ~6.7e-5 rad
__device__ __forceinline__ float acos_fast(float x) {
    float t = fabsf(x);
    float r = sqrtf(1.f - t);
    float p = fmaf(fmaf(fmaf(-0.0187293f, t, 0.0742610f), t, -0.2121144f), t, 1.5707288f);
    float ac = r * p;
    return (x < 0.f) ? (3.14159265358979f - ac) : ac;
}

// one coefficient pair contribution. own=(oR,oI) this lane's image; rec=(rR,rI)
// partner's image. img=0: own is target; img=1: rec is target. Watson's |a0-a1|,
// phase dot and norms are role-symmetric -> only a0 (feeding s) needs a select.
__device__ __forceinline__ void coef2(float oR, float oI, float rR, float rI,
                                      int idx, int img,
                                      const float* __restrict__ t_tab,
                                      const float* __restrict__ wlt_tab,
                                      const float* __restrict__ wp_tab,
                                      float lum, float omw_llum, float w,
                                      bool b1, float beta,
                                      float& sumW, float& sumP) {
    float oRe = oR + EPSf, oIe = oI + EPSf;
    float rRe = rR + EPSf, rIe = rI + EPSf;
    float aO = sqrtf(fmaf(oRe, oRe, oIe * oIe));
    float aR = sqrtf(fmaf(rRe, rRe, rIe * rIe));
    float a0 = img ? aR : aO;                       // target amplitude
    float dx = fabsf(aO - aR);
    // bb = (a0+eps)^w * t_l^(1-w) via single log2/exp2
    float l0 = __log2f(a0 + EPSf);
    float bb = exp2f(fmaf(w, l0, wlt_tab[idx] + omw_llum));
    float t_l = t_tab[idx] * lum;
    float e = __expf(bb - t_l);
    float f0 = __builtin_amdgcn_rcpf(1.f + e);      // softmax weight of t_l
    float s = fmaf(f0, t_l - bb, bb);
    float x = dx * __builtin_amdgcn_rcpf(s);
    if (b1) sumW += x;                              // epsilons folded in at end
    else    sumW += __powf(x + EPSf, beta) + EPSf;
    // phase: cos(p0-p1) via dot/norms (imag WITHOUT eps, real WITH eps) — symmetric
    float dot = fmaf(oRe, rRe, oI * rI);
    float n0 = fmaf(oRe, oRe, oI * oI);
    float n1 = fmaf(rRe, rRe, rI * rI);
    float nn = fmaxf(n0 * n1, 1e-36f);
    float cosd = dot * __builtin_amdgcn_rsqf(nn) * (1.f - 1e-7f);
    cosd = fminf(fmaxf(cosd, -1.f), 1.f);
    sumP = fmaf(acos_fast(cosd), wp_tab[idx], sumP);
}

// half-exchange one slot pair: even lane owns u=S (sends u=S+4), odd owns u=S+4
#define PAIRC(V, S, LOr, LOi, HIr, HIi) do { \
    float sdr = img ? (LOr) : (HIr), sdi = img ? (LOi) : (HIi); \
    float rcr = __shfl_xor(sdr, 1, 64), rci = __shfl_xor(sdi, 1, 64); \
    float owr = img ? (HIr) : (LOr), owi = img ? (HIi) : (LOi); \
    coef2(owr, owi, rcr, rci, base20 + (S) * 5 + (V), img, t_tab, wlt_tab, wp_tab, \
          lum, omw_llum, w, b1, beta, sumW, sumP); \
} while (0)

#define COEFS2(V) do { \
    PAIRC(V, 0, X0r, X0i, X4r, X4i); \
    PAIRC(V, 1, X1r, X1i, X5r, X5i); \
    PAIRC(V, 2, X2r, X2i, X6r, X6i); \
    PAIRC(V, 3, X3r, X3i, X7r, X7i); \
} while (0)

// ---------------- kernel C: main fused compute (2 lanes per block-pair) -------
__global__ __launch_bounds__(WG, 2) void kC(const float* __restrict__ tgt,
                                            const float* __restrict__ inp,
                                            const float* __restrict__ t_tild,
                                            const float* __restrict__ alphaP,
                                            const float* __restrict__ wtP,
                                            const float* __restrict__ betaP,
                                            const float* __restrict__ wptP,
                                            const float* __restrict__ avgP,
                                            float* __restrict__ partW,
                                            float* __restrict__ partP) {
    __shared__ float t_tab[40], wlt_tab[40], wp_tab[40];
    float w = 1.f / (1.f + __expf(-wtP[0]));
    if (threadIdx.x < 40) {
        float tt = t_tild[threadIdx.x];
        t_tab[threadIdx.x] = __expf(tt);
        wlt_tab[threadIdx.x] = (1.f - w) * tt * LOG2E;  // (1-w)*log2(t)
        wp_tab[threadIdx.x] = __expf(wptP[threadIdx.x]);
    }
    __syncthreads();
    float alpha = alphaP[0];
    float beta = betaP[0];
    float avg = avgP[0];
    float lavg = __log2f(avg + EPSf);
    bool b1 = (beta == 1.0f);

    int gid = blockIdx.x * WG + threadIdx.x;
    int p = gid >> 1;          // block-pair index
    int img = gid & 1;         // 0 = target, 1 = input  (== lane parity)
    int base20 = img * 20;
    int n = p >> 12, k = p & 4095;
    int bi = k >> 6, bj = k & 63;
    size_t off = (size_t)n * (IMG_H * IMG_W) + (size_t)(bi * 8) * IMG_W + bj * 8;
    const float* src = (img ? inp : tgt) + off;

    // row FFT state for ONE image: 64 named scalars
    DECL8(t0); DECL8(t1); DECL8(t2); DECL8(t3);
    DECL8(t4); DECL8(t5); DECL8(t6); DECL8(t7);
    LOADROW(src, 0, t0); LOADROW(src, 1, t1); LOADROW(src, 2, t2); LOADROW(src, 3, t3);
    LOADROW(src, 4, t4); LOADROW(src, 5, t5); LOADROW(src, 6, t6); LOADROW(src, 7, t7);

    float sumW = 0.f, sumP = 0.f;
    float lum = 0.f, omw_llum = 0.f;

    { // v = 0 : real column, component 0
        CFFT8M(X, t0_0, 0.f, t1_0, 0.f, t2_0, 0.f, t3_0, 0.f,
                  t4_0, 0.f, t5_0, 0.f, t6_0, 0.f, t7_0, 0.f)
        // lum from TARGET's DC amp (even lane owns it)
        float rr = X0r + EPSf, ii = X0i + EPSf;
        float myamp = sqrtf(fmaf(rr, rr, ii * ii));
        float oamp = __shfl_xor(myamp, 1, 64);
        float amp00 = img ? oamp : myamp;
        float llum = alpha * (__log2f(amp00 + EPSf) - lavg);
        lum = exp2f(llum);
        omw_llum = (1.f - w) * llum;
        COEFS2(0);
    }
    { // v = 1 : components 1 (re), 2 (im)
        CFFT8M(X, t0_1, t0_2, t1_1, t1_2, t2_1, t2_2, t3_1, t3_2,
                  t4_1, t4_2, t5_1, t5_2, t6_1, t6_2, t7_1, t7_2)
        COEFS2(1);
    }
    { // v = 2 : components 3, 4
        CFFT8M(X, t0_3, t0_4, t1_3, t1_4, t2_3, t2_4, t3_3, t3_4,
                  t4_3, t4_4, t5_3, t5_4, t6_3, t6_4, t7_3, t7_4)
        COEFS2(2);
    }
    { // v = 3 : components 5, 6
        CFFT8M(X, t0_5, t0_6, t1_5, t1_6, t2_5, t2_6, t3_5, t3_6,
                  t4_5, t4_6, t5_5, t5_6, t6_5, t6_6, t7_5, t7_6)
        COEFS2(3);
    }
    { // v = 4 : real column, component 7
        CFFT8M(X, t0_7, 0.f, t1_7, 0.f, t2_7, 0.f, t3_7, 0.f,
                  t4_7, 0.f, t5_7, 0.f, t6_7, 0.f, t7_7, 0.f)
        COEFS2(4);
    }

    if (b1) sumW += 20.f * 2.f * EPSf;   // fold per-term (+eps)^1 + eps

    float wW = wave_red(sumW);
    float wP = wave_red(sumP);
    __shared__ float redW[4], redP[4];
    if ((threadIdx.x & 63) == 0) { redW[threadIdx.x >> 6] = wW; redP[threadIdx.x >> 6] = wP; }
    __syncthreads();
    if (threadIdx.x == 0) {
        partW[blockIdx.x] = (redW[0] + redW[1]) + (redW[2] + redW[3]);
        partP[blockIdx.x] = (redP[0] + redP[1]) + (redP[2] + redP[3]);
    }
}

// ---------------- kernel D: per-image final ----------------------------------
__global__ __launch_bounds__(64) void kD(const float* __restrict__ partW,
                                         const float* __restrict__ partP,
                                         const float* __restrict__ betaP,
                                         float* __restrict__ out) {
    int n = threadIdx.x;
    float sW = 0.f, sP = 0.f;
#pragma unroll
    for (int c = 0; c < CHUNKS; c++) {
        sW += partW[n * CHUNKS + c];
        sP += partP[n * CHUNKS + c];
    }
    float beta = betaP[0];
    float wat = (beta == 1.0f) ? sW : __powf(sW, 1.0f / beta);
    out[n] = wat + sP;
}

extern "C" void kernel_launch(void* const* d_in, const int* in_sizes, int n_in,
                              void* d_out, int out_size, void* d_ws, size_t ws_size,
                              hipStream_t stream) {
    const float* inp    = (const float*)d_in[0];
    const float* tgt    = (const float*)d_in[1];
    const float* t_tild = (const float*)d_in[2];
    const float* alphaP = (const float*)d_in[3];
    const float* wtP    = (const float*)d_in[4];
    const float* betaP  = (const float*)d_in[5];
    const float* wptP   = (const float*)d_in[6];
    float* out = (float*)d_out;
    float* ws = (float*)d_ws;
    float* partA = ws;           // [1024]
    float* avgV  = ws + 1024;    // [1]
    float* partW = ws + 1056;    // [2048]
    float* partP = ws + 3104;    // [2048]

    hipLaunchKernelGGL(kA, dim3(NWG), dim3(WG), 0, stream, tgt, partA);
    hipLaunchKernelGGL(kB, dim3(1), dim3(1024), 0, stream, partA, avgV);
    hipLaunchKernelGGL(kC, dim3(NWG2), dim3(WG), 0, stream, tgt, inp, t_tild,
                       alphaP, wtP, betaP, wptP, avgV, partW, partP);
    hipLaunchKernelGGL(kD, dim3(1), dim3(64), 0, stream, partW, partP, betaP, out);
}

// Round 7
// 57.146 us; speedup vs baseline: 4.7885x; 1.0515x over previous
//
#include <hip/hip_runtime.h>
#include <math.h>

#define EPSf 1e-10f
#define IMG_N 64
#define IMG_H 512
#define IMG_W 512
#define KBLK 4096                  // 64x64 blocks per image
#define TOTAL_BLK (IMG_N * KBLK)   // 262144
#define WG 256
#define NWG (TOTAL_BLK / WG)       // 1024 (kA)
#define NWG2 (TOTAL_BLK * 2 / WG)  // 2048 (kC: 2 lanes per block-pair)
#define CHUNKS 32                  // kC workgroups per image (2048/64)

#define KCc 0.70710678118654752440f
#define SCc (1.0f / 64.0f)
#define LOG2E 1.44269504088896340736f

#define FSQRT(x) __builtin_amdgcn_sqrtf(x)
#define FRCP(x)  __builtin_amdgcn_rcpf(x)

__device__ __forceinline__ float wave_red(float v) {
#pragma unroll
    for (int o = 32; o > 0; o >>= 1) v += __shfl_down(v, o, 64);
    return v;
}

// ---------------- kernel A: per-block DC amplitude of target, partial sums ----
__global__ __launch_bounds__(WG) void kA(const float* __restrict__ tgt,
                                         float* __restrict__ partA) {
    int gid = blockIdx.x * WG + threadIdx.x;
    int n = gid >> 12;
    int k = gid & 4095;
    int bi = k >> 6, bj = k & 63;
    const float* p = tgt + (size_t)n * (IMG_H * IMG_W) + (size_t)(bi * 8) * IMG_W + bj * 8;
    float s = 0.f;
#pragma unroll
    for (int r = 0; r < 8; r++) {
        float4 a = *(const float4*)(p + (size_t)r * IMG_W);
        float4 b = *(const float4*)(p + (size_t)r * IMG_W + 4);
        s += ((a.x + a.y) + (a.z + a.w)) + ((b.x + b.y) + (b.z + b.w));
    }
    float dc = s * (1.0f / 64.0f);                 // rfft2 DC / b^2
    float amp = sqrtf((dc + EPSf) * (dc + EPSf) + EPSf * EPSf);
    float wv = wave_red(amp);
    __shared__ float red[4];
    if ((threadIdx.x & 63) == 0) red[threadIdx.x >> 6] = wv;
    __syncthreads();
    if (threadIdx.x == 0) partA[blockIdx.x] = (red[0] + red[1]) + (red[2] + red[3]);
}

// ---------------- kernel B: reduce 1024 partials -> avg_lum -------------------
__global__ __launch_bounds__(1024) void kB(const float* __restrict__ partA,
                                           float* __restrict__ avgOut) {
    float v = partA[threadIdx.x];
    float wv = wave_red(v);
    __shared__ float red[16];
    if ((threadIdx.x & 63) == 0) red[threadIdx.x >> 6] = wv;
    __syncthreads();
    if (threadIdx.x == 0) {
        float s = 0.f;
#pragma unroll
        for (int i = 0; i < 16; i++) s += red[i];
        avgOut[0] = s * (1.0f / (float)TOTAL_BLK);
    }
}

// row real FFT-8 -> 8 NAMED scalars [c0, c1r, c1i, c2r, c2i, c3r, c3i, c4], /64
#define ROWFFT(A, B, P) do { \
    float s02 = (A).x + (B).x, d02 = (A).x - (B).x; \
    float s26 = (A).z + (B).z, d26 = (A).z - (B).z; \
    float s13 = (A).y + (B).y, d13 = (A).y - (B).y; \
    float s37 = (A).w + (B).w, d37 = (A).w - (B).w; \
    float e0 = s02 + s26, e2 = s02 - s26; \
    float o0 = s13 + s37, o2 = s13 - s37; \
    float cp = KCc * (d13 - d37), cm = KCc * (d13 + d37); \
    P##_0 = SCc * (e0 + o0);  P##_1 = SCc * (d02 + cp); \
    P##_2 = SCc * (-d26 - cm); P##_3 = SCc * e2; \
    P##_4 = SCc * (-o2);      P##_5 = SCc * (d02 - cp); \
    P##_6 = SCc * (d26 - cm); P##_7 = SCc * (e0 - o0); \
} while (0)

#define DECL8(P) float P##_0, P##_1, P##_2, P##_3, P##_4, P##_5, P##_6, P##_7

#define LOADROW(ptr, r, P) do { \
    float4 A = *(const float4*)((ptr) + (size_t)(r) * IMG_W); \
    float4 B = *(const float4*)((ptr) + (size_t)(r) * IMG_W + 4); \
    ROWFFT(A, B, P); \
} while (0)

// complex FFT-8 on 16 scalar inputs -> 16 NAMED scalar outputs PFX0r..PFX7i
#define CFFT8M(PFX, x0r,x0i,x1r,x1i,x2r,x2i,x3r,x3i,x4r,x4i,x5r,x5i,x6r,x6i,x7r,x7i) \
    float PFX##0r, PFX##0i, PFX##1r, PFX##1i, PFX##2r, PFX##2i, PFX##3r, PFX##3i, \
          PFX##4r, PFX##4i, PFX##5r, PFX##5i, PFX##6r, PFX##6i, PFX##7r, PFX##7i; \
    { \
        float t0r = (x0r) + (x4r), t0i = (x0i) + (x4i); \
        float t1r = (x0r) - (x4r), t1i = (x0i) - (x4i); \
        float t2r = (x2r) + (x6r), t2i = (x2i) + (x6i); \
        float t3r = (x2r) - (x6r), t3i = (x2i) - (x6i); \
        float E0r = t0r + t2r, E0i = t0i + t2i; \
        float E2r = t0r - t2r, E2i = t0i - t2i; \
        float E1r = t1r + t3i, E1i = t1i - t3r; \
        float E3r = t1r - t3i, E3i = t1i + t3r; \
        float u0r = (x1r) + (x5r), u0i = (x1i) + (x5i); \
        float u1r = (x1r) - (x5r), u1i = (x1i) - (x5i); \
        float u2r = (x3r) + (x7r), u2i = (x3i) + (x7i); \
        float u3r = (x3r) - (x7r), u3i = (x3i) - (x7i); \
        float O0r = u0r + u2r, O0i = u0i + u2i; \
        float O2r = u0r - u2r, O2i = u0i - u2i; \
        float O1r = u1r + u3i, O1i = u1i - u3r; \
        float O3r = u1r - u3i, O3i = u1i + u3r; \
        float W1r = KCc * (O1r + O1i), W1i = KCc * (O1i - O1r); \
        float W2r = O2i,               W2i = -O2r; \
        float W3r = KCc * (O3i - O3r), W3i = -KCc * (O3r + O3i); \
        PFX##0r = E0r + O0r; PFX##0i = E0i + O0i; \
        PFX##1r = E1r + W1r; PFX##1i = E1i + W1i; \
        PFX##2r = E2r + W2r; PFX##2i = E2i + W2i; \
        PFX##3r = E3r + W3r; PFX##3i = E3i + W3i; \
        PFX##4r = E0r - O0r; PFX##4i = E0i - O0i; \
        PFX##5r = E1r - W1r; PFX##5i = E1i - W1i; \
        PFX##6r = E2r - W2r; PFX##6i = E2i - W2i; \
        PFX##7r = E3r - W3r; PFX##7i = E3i - W3i; \
    }

// fast acos: Abramowitz-Stegun 4.4.45 (3-term), max err ~6.7e-5 rad
__device__ __forceinline__ float acos_fast(float x) {
    float t = fabsf(x);
    float r = FSQRT(1.f - t);
    float p = fmaf(fmaf(fmaf(-0.0187293f, t, 0.0742610f), t, -0.2121144f), t, 1.5707288f);
    float ac = r * p;
    return (x < 0.f) ? (3.14159265358979f - ac) : ac;
}

// one coefficient pair contribution. own=(oR,oI) this lane's image; rec=(rR,rI)
// partner's image. img=0: own is target; img=1: rec is target.
__device__ __forceinline__ void coef2(float oR, float oI, float rR, float rI,
                                      int idx, int img,
                                      const float2* __restrict__ tw_tab,
                                      const float* __restrict__ wp_tab,
                                      float lum, float omw_llum, float w,
                                      bool b1, float beta,
                                      float& sumW, float& sumP) {
    float oRe = oR + EPSf, oIe = oI + EPSf;
    float rRe = rR + EPSf, rIe = rI + EPSf;
    float aO = FSQRT(fmaf(oRe, oRe, oIe * oIe));
    float aR = FSQRT(fmaf(rRe, rRe, rIe * rIe));
    float a0 = img ? aR : aO;                       // target amplitude
    float dx = fabsf(aO - aR);
    float2 tw = tw_tab[idx];                        // {t, (1-w)*log2(t)}
    // bb = (a0+eps)^w * t_l^(1-w) via single log2/exp2
    float l0 = __log2f(a0 + EPSf);
    float bb = exp2f(fmaf(w, l0, tw.y + omw_llum));
    float t_l = tw.x * lum;
    float e = __expf(bb - t_l);
    // s = (t_l + bb*e)/(1+e)  =>  x = dx*(1+e)/(t_l + bb*e): one rcp
    float x = dx * (1.f + e) * FRCP(fmaf(bb, e, t_l));
    if (b1) sumW += x;                              // epsilons folded in at end
    else    sumW += __powf(x + EPSf, beta) + EPSf;
    // phase: cos(p0-p1). norms ~= (aO*aR)^2 (eps-order difference, tol 967)
    float dot = fmaf(oRe, rRe, oI * rI);
    float cosd = dot * FRCP(fmaxf(aO * aR, 1e-30f)) * (1.f - 1e-7f);
    cosd = fminf(fmaxf(cosd, -1.f), 1.f);
    sumP = fmaf(acos_fast(cosd), wp_tab[idx], sumP);
}

// half-exchange one slot pair: even lane owns u=S (sends u=S+4), odd owns u=S+4
#define PAIRC(V, S, LOr, LOi, HIr, HIi) do { \
    float sdr = img ? (LOr) : (HIr), sdi = img ? (LOi) : (HIi); \
    float rcr = __shfl_xor(sdr, 1, 64), rci = __shfl_xor(sdi, 1, 64); \
    float owr = img ? (HIr) : (LOr), owi = img ? (HIi) : (LOi); \
    coef2(owr, owi, rcr, rci, base20 + (S) * 5 + (V), img, tw_tab, wp_tab, \
          lum, omw_llum, w, b1, beta, sumW, sumP); \
} while (0)

#define COEFS2(V) do { \
    PAIRC(V, 0, X0r, X0i, X4r, X4i); \
    PAIRC(V, 1, X1r, X1i, X5r, X5i); \
    PAIRC(V, 2, X2r, X2i, X6r, X6i); \
    PAIRC(V, 3, X3r, X3i, X7r, X7i); \
} while (0)

// ---------------- kernel C: main fused compute (2 lanes per block-pair) -------
__global__ __launch_bounds__(WG, 2) void kC(const float* __restrict__ tgt,
                                            const float* __restrict__ inp,
                                            const float* __restrict__ t_tild,
                                            const float* __restrict__ alphaP,
                                            const float* __restrict__ wtP,
                                            const float* __restrict__ betaP,
                                            const float* __restrict__ wptP,
                                            const float* __restrict__ avgP,
                                            float* __restrict__ partW,
                                            float* __restrict__ partP) {
    __shared__ float2 tw_tab[40];
    __shared__ float wp_tab[40];
    float w = 1.f / (1.f + __expf(-wtP[0]));
    if (threadIdx.x < 40) {
        float tt = t_tild[threadIdx.x];
        tw_tab[threadIdx.x] = make_float2(__expf(tt), (1.f - w) * tt * LOG2E);
        wp_tab[threadIdx.x] = __expf(wptP[threadIdx.x]);
    }
    __syncthreads();
    float alpha = alphaP[0];
    float beta = betaP[0];
    float avg = avgP[0];
    float lavg = __log2f(avg + EPSf);
    bool b1 = (beta == 1.0f);

    int gid = blockIdx.x * WG + threadIdx.x;
    int p = gid >> 1;          // block-pair index
    int img = gid & 1;         // 0 = target, 1 = input  (== lane parity)
    int base20 = img * 20;
    int n = p >> 12, k = p & 4095;
    int bi = k >> 6, bj = k & 63;
    size_t off = (size_t)n * (IMG_H * IMG_W) + (size_t)(bi * 8) * IMG_W + bj * 8;
    const float* src = (img ? inp : tgt) + off;

    // row FFT state for ONE image: 64 named scalars
    DECL8(t0); DECL8(t1); DECL8(t2); DECL8(t3);
    DECL8(t4); DECL8(t5); DECL8(t6); DECL8(t7);
    LOADROW(src, 0, t0); LOADROW(src, 1, t1); LOADROW(src, 2, t2); LOADROW(src, 3, t3);
    LOADROW(src, 4, t4); LOADROW(src, 5, t5); LOADROW(src, 6, t6); LOADROW(src, 7, t7);

    float sumW = 0.f, sumP = 0.f;
    float lum = 0.f, omw_llum = 0.f;

    { // v = 0 : real column, component 0
        CFFT8M(X, t0_0, 0.f, t1_0, 0.f, t2_0, 0.f, t3_0, 0.f,
                  t4_0, 0.f, t5_0, 0.f, t6_0, 0.f, t7_0, 0.f)
        // lum from TARGET's DC amp (even lane owns it)
        float rr = X0r + EPSf, ii = X0i + EPSf;
        float myamp = FSQRT(fmaf(rr, rr, ii * ii));
        float oamp = __shfl_xor(myamp, 1, 64);
        float amp00 = img ? oamp : myamp;
        float llum = alpha * (__log2f(amp00 + EPSf) - lavg);
        lum = exp2f(llum);
        omw_llum = (1.f - w) * llum;
        COEFS2(0);
    }
    { // v = 1 : components 1 (re), 2 (im)
        CFFT8M(X, t0_1, t0_2, t1_1, t1_2, t2_1, t2_2, t3_1, t3_2,
                  t4_1, t4_2, t5_1, t5_2, t6_1, t6_2, t7_1, t7_2)
        COEFS2(1);
    }
    { // v = 2 : components 3, 4
        CFFT8M(X, t0_3, t0_4, t1_3, t1_4, t2_3, t2_4, t3_3, t3_4,
                  t4_3, t4_4, t5_3, t5_4, t6_3, t6_4, t7_3, t7_4)
        COEFS2(2);
    }
    { // v = 3 : components 5, 6
        CFFT8M(X, t0_5, t0_6, t1_5, t1_6, t2_5, t2_6, t3_5, t3_6,
                  t4_5, t4_6, t5_5, t5_6, t6_5, t6_6, t7_5, t7_6)
        COEFS2(3);
    }
    { // v = 4 : real column, component 7
        CFFT8M(X, t0_7, 0.f, t1_7, 0.f, t2_7, 0.f, t3_7, 0.f,
                  t4_7, 0.f, t5_7, 0.f, t6_7, 0.f, t7_7, 0.f)
        COEFS2(4);
    }

    if (b1) sumW += 20.f * 2.f * EPSf;   // fold per-term (+eps)^1 + eps

    float wW = wave_red(sumW);
    float wP = wave_red(sumP);
    __shared__ float redW[4], redP[4];
    if ((threadIdx.x & 63) == 0) { redW[threadIdx.x >> 6] = wW; redP[threadIdx.x >> 6] = wP; }
    __syncthreads();
    if (threadIdx.x == 0) {
        partW[blockIdx.x] = (redW[0] + redW[1]) + (redW[2] + redW[3]);
        partP[blockIdx.x] = (redP[0] + redP[1]) + (redP[2] + redP[3]);
    }
}

// ---------------- kernel D: per-image final ----------------------------------
__global__ __launch_bounds__(64) void kD(const float* __restrict__ partW,
                                         const float* __restrict__ partP,
                                         const float* __restrict__ betaP,
                                         float* __restrict__ out) {
    int n = threadIdx.x;
    float sW = 0.f, sP = 0.f;
#pragma unroll
    for (int c = 0; c < CHUNKS; c++) {
        sW += partW[n * CHUNKS + c];
        sP += partP[n * CHUNKS + c];
    }
    float beta = betaP[0];
    float wat = (beta == 1.0f) ? sW : __powf(sW, 1.0f / beta);
    out[n] = wat + sP;
}

extern "C" void kernel_launch(void* const* d_in, const int* in_sizes, int n_in,
                              void* d_out, int out_size, void* d_ws, size_t ws_size,
                              hipStream_t stream) {
    const float* inp    = (const float*)d_in[0];
    const float* tgt    = (const float*)d_in[1];
    const float* t_tild = (const float*)d_in[2];
    const float* alphaP = (const float*)d_in[3];
    const float* wtP    = (const float*)d_in[4];
    const float* betaP  = (const float*)d_in[5];
    const float* wptP   = (const float*)d_in[6];
    float* out = (float*)d_out;
    float* ws = (float*)d_ws;
    float* partA = ws;           // [1024]
    float* avgV  = ws + 1024;    // [1]
    float* partW = ws + 1056;    // [2048]
    float* partP = ws + 3104;    // [2048]

    hipLaunchKernelGGL(kA, dim3(NWG), dim3(WG), 0, stream, tgt, partA);
    hipLaunchKernelGGL(kB, dim3(1), dim3(1024), 0, stream, partA, avgV);
    hipLaunchKernelGGL(kC, dim3(NWG2), dim3(WG), 0, stream, tgt, inp, t_tild,
                       alphaP, wtP, betaP, wptP, avgV, partW, partP);
    hipLaunchKernelGGL(kD, dim3(1), dim3(64), 0, stream, partW, partP, betaP, out);
}

// Round 8
// 54.152 us; speedup vs baseline: 5.0534x; 1.0553x over previous
//
#include <hip/hip_runtime.h>
#include <math.h>

#define EPSf 1e-10f
#define IMG_N 64
#define IMG_H 512
#define IMG_W 512
#define KBLK 4096                  // 64x64 blocks per image
#define TOTAL_BLK (IMG_N * KBLK)   // 262144
#define WG 256
#define NWG (TOTAL_BLK / WG)       // 1024 (kA)
#define NWG2 (TOTAL_BLK * 2 / WG)  // 2048 (kC: 2 lanes per block-pair)
#define CHUNKS 32                  // kC workgroups per image (2048/64)

#define KCc 0.70710678118654752440f
#define SCc (1.0f / 64.0f)
#define LOG2E 1.44269504088896340736f

#define FSQRT(x) __builtin_amdgcn_sqrtf(x)
#define FRCP(x)  __builtin_amdgcn_rcpf(x)

// lane^1 exchange via DPP quad_perm [1,0,3,2] — pure VALU, no DS op
__device__ __forceinline__ float dpp_xor1(float x) {
    int i = __builtin_bit_cast(int, x);
    i = __builtin_amdgcn_mov_dpp(i, 0xB1, 0xF, 0xF, true);
    return __builtin_bit_cast(float, i);
}

__device__ __forceinline__ float wave_red(float v) {
#pragma unroll
    for (int o = 32; o > 0; o >>= 1) v += __shfl_down(v, o, 64);
    return v;
}

// ---------------- kernel A: per-block DC amplitude of target, partial sums ----
__global__ __launch_bounds__(WG) void kA(const float* __restrict__ tgt,
                                         float* __restrict__ partA) {
    int gid = blockIdx.x * WG + threadIdx.x;
    int n = gid >> 12;
    int k = gid & 4095;
    int bi = k >> 6, bj = k & 63;
    const float* p = tgt + (size_t)n * (IMG_H * IMG_W) + (size_t)(bi * 8) * IMG_W + bj * 8;
    float s = 0.f;
#pragma unroll
    for (int r = 0; r < 8; r++) {
        float4 a = *(const float4*)(p + (size_t)r * IMG_W);
        float4 b = *(const float4*)(p + (size_t)r * IMG_W + 4);
        s += ((a.x + a.y) + (a.z + a.w)) + ((b.x + b.y) + (b.z + b.w));
    }
    float dc = s * (1.0f / 64.0f);                 // rfft2 DC / b^2
    float amp = sqrtf((dc + EPSf) * (dc + EPSf) + EPSf * EPSf);
    float wv = wave_red(amp);
    __shared__ float red[4];
    if ((threadIdx.x & 63) == 0) red[threadIdx.x >> 6] = wv;
    __syncthreads();
    if (threadIdx.x == 0) partA[blockIdx.x] = (red[0] + red[1]) + (red[2] + red[3]);
}

// ---------------- kernel B: reduce 1024 partials -> avg_lum -------------------
__global__ __launch_bounds__(1024) void kB(const float* __restrict__ partA,
                                           float* __restrict__ avgOut) {
    float v = partA[threadIdx.x];
    float wv = wave_red(v);
    __shared__ float red[16];
    if ((threadIdx.x & 63) == 0) red[threadIdx.x >> 6] = wv;
    __syncthreads();
    if (threadIdx.x == 0) {
        float s = 0.f;
#pragma unroll
        for (int i = 0; i < 16; i++) s += red[i];
        avgOut[0] = s * (1.0f / (float)TOTAL_BLK);
    }
}

// row real FFT-8 -> 8 NAMED scalars [c0, c1r, c1i, c2r, c2i, c3r, c3i, c4], /64
#define ROWFFT(A, B, P) do { \
    float s02 = (A).x + (B).x, d02 = (A).x - (B).x; \
    float s26 = (A).z + (B).z, d26 = (A).z - (B).z; \
    float s13 = (A).y + (B).y, d13 = (A).y - (B).y; \
    float s37 = (A).w + (B).w, d37 = (A).w - (B).w; \
    float e0 = s02 + s26, e2 = s02 - s26; \
    float o0 = s13 + s37, o2 = s13 - s37; \
    float cp = KCc * (d13 - d37), cm = KCc * (d13 + d37); \
    P##_0 = SCc * (e0 + o0);  P##_1 = SCc * (d02 + cp); \
    P##_2 = SCc * (-d26 - cm); P##_3 = SCc * e2; \
    P##_4 = SCc * (-o2);      P##_5 = SCc * (d02 - cp); \
    P##_6 = SCc * (d26 - cm); P##_7 = SCc * (e0 - o0); \
} while (0)

#define DECL8(P) float P##_0, P##_1, P##_2, P##_3, P##_4, P##_5, P##_6, P##_7

#define LOADROW(ptr, r, P) do { \
    float4 A = *(const float4*)((ptr) + (size_t)(r) * IMG_W); \
    float4 B = *(const float4*)((ptr) + (size_t)(r) * IMG_W + 4); \
    ROWFFT(A, B, P); \
} while (0)

// complex FFT-8 on 16 scalar inputs -> 16 NAMED scalar outputs PFX0r..PFX7i
#define CFFT8M(PFX, x0r,x0i,x1r,x1i,x2r,x2i,x3r,x3i,x4r,x4i,x5r,x5i,x6r,x6i,x7r,x7i) \
    float PFX##0r, PFX##0i, PFX##1r, PFX##1i, PFX##2r, PFX##2i, PFX##3r, PFX##3i, \
          PFX##4r, PFX##4i, PFX##5r, PFX##5i, PFX##6r, PFX##6i, PFX##7r, PFX##7i; \
    { \
        float t0r = (x0r) + (x4r), t0i = (x0i) + (x4i); \
        float t1r = (x0r) - (x4r), t1i = (x0i) - (x4i); \
        float t2r = (x2r) + (x6r), t2i = (x2i) + (x6i); \
        float t3r = (x2r) - (x6r), t3i = (x2i) - (x6i); \
        float E0r = t0r + t2r, E0i = t0i + t2i; \
        float E2r = t0r - t2r, E2i = t0i - t2i; \
        float E1r = t1r + t3i, E1i = t1i - t3r; \
        float E3r = t1r - t3i, E3i = t1i + t3r; \
        float u0r = (x1r) + (x5r), u0i = (x1i) + (x5i); \
        float u1r = (x1r) - (x5r), u1i = (x1i) - (x5i); \
        float u2r = (x3r) + (x7r), u2i = (x3i) + (x7i); \
        float u3r = (x3r) - (x7r), u3i = (x3i) - (x7i); \
        float O0r = u0r + u2r, O0i = u0i + u2i; \
        float O2r = u0r - u2r, O2i = u0i - u2i; \
        float O1r = u1r + u3i, O1i = u1i - u3r; \
        float O3r = u1r - u3i, O3i = u1i + u3r; \
        float W1r = KCc * (O1r + O1i), W1i = KCc * (O1i - O1r); \
        float W2r = O2i,               W2i = -O2r; \
        float W3r = KCc * (O3i - O3r), W3i = -KCc * (O3r + O3i); \
        PFX##0r = E0r + O0r; PFX##0i = E0i + O0i; \
        PFX##1r = E1r + W1r; PFX##1i = E1i + W1i; \
        PFX##2r = E2r + W2r; PFX##2i = E2i + W2i; \
        PFX##3r = E3r + W3r; PFX##3i = E3i + W3i; \
        PFX##4r = E0r - O0r; PFX##4i = E0i - O0i; \
        PFX##5r = E1r - W1r; PFX##5i = E1i - W1i; \
        PFX##6r = E2r - W2r; PFX##6i = E2i - W2i; \
        PFX##7r = E3r - W3r; PFX##7i = E3i - W3i; \
    }

// fast acos: Abramowitz-Stegun 4.4.45 (3-term), max err ~6.7e-5 rad
__device__ __forceinline__ float acos_fast(float x) {
    float t = fabsf(x);
    float r = FSQRT(1.f - t);
    float p = fmaf(fmaf(fmaf(-0.0187293f, t, 0.0742610f), t, -0.2121144f), t, 1.5707288f);
    float ac = r * p;
    return (x < 0.f) ? (3.14159265358979f - ac) : ac;
}

// one coefficient pair contribution. own=(oR,oI) this lane's image; rec=(rR,rI)
// partner's image. img=0: own is target; img=1: rec is target.
__device__ __forceinline__ void coef2(float oR, float oI, float rR, float rI,
                                      int idx, int img,
                                      const float2* __restrict__ tw_tab,
                                      const float* __restrict__ wp_tab,
                                      float lum, float omw_llum, float w,
                                      bool b1, float beta,
                                      float& sumW, float& sumP) {
    float oRe = oR + EPSf, oIe = oI + EPSf;
    float rRe = rR + EPSf, rIe = rI + EPSf;
    float aO = FSQRT(fmaf(oRe, oRe, oIe * oIe));
    float aR = FSQRT(fmaf(rRe, rRe, rIe * rIe));
    float a0 = img ? aR : aO;                       // target amplitude
    float dx = fabsf(aO - aR);
    float2 tw = tw_tab[idx];                        // {t, (1-w)*log2(t)}
    // bb = (a0+eps)^w * t_l^(1-w) via single log2/exp2
    float l0 = __log2f(a0 + EPSf);
    float bb = exp2f(fmaf(w, l0, tw.y + omw_llum));
    float t_l = tw.x * lum;
    float e = __expf(bb - t_l);
    // s = (t_l + bb*e)/(1+e)  =>  x = dx*(1+e)/(t_l + bb*e): one rcp
    float x = dx * (1.f + e) * FRCP(fmaf(bb, e, t_l));
    if (b1) sumW += x;                              // epsilons folded in at end
    else    sumW += __powf(x + EPSf, beta) + EPSf;
    // phase: cos(p0-p1). norms ~= (aO*aR)^2 (eps-order difference, tol 967)
    float dot = fmaf(oRe, rRe, oI * rI);
    float cosd = dot * FRCP(fmaxf(aO * aR, 1e-30f)) * (1.f - 1e-7f);
    cosd = fminf(fmaxf(cosd, -1.f), 1.f);
    sumP = fmaf(acos_fast(cosd), wp_tab[idx], sumP);
}

// half-exchange one slot pair: even lane owns u=S (sends u=S+4), odd owns u=S+4
#define PAIRC(V, S, LOr, LOi, HIr, HIi) do { \
    float sdr = img ? (LOr) : (HIr), sdi = img ? (LOi) : (HIi); \
    float rcr = dpp_xor1(sdr), rci = dpp_xor1(sdi); \
    float owr = img ? (HIr) : (LOr), owi = img ? (HIi) : (LOi); \
    coef2(owr, owi, rcr, rci, base20 + (S) * 5 + (V), img, tw_tab, wp_tab, \
          lum, omw_llum, w, b1, beta, sumW, sumP); \
} while (0)

#define COEFS2(V) do { \
    PAIRC(V, 0, X0r, X0i, X4r, X4i); \
    PAIRC(V, 1, X1r, X1i, X5r, X5i); \
    PAIRC(V, 2, X2r, X2i, X6r, X6i); \
    PAIRC(V, 3, X3r, X3i, X7r, X7i); \
} while (0)

// ---------------- kernel C: main fused compute (2 lanes per block-pair) -------
__global__ __launch_bounds__(WG, 2) void kC(const float* __restrict__ tgt,
                                            const float* __restrict__ inp,
                                            const float* __restrict__ t_tild,
                                            const float* __restrict__ alphaP,
                                            const float* __restrict__ wtP,
                                            const float* __restrict__ betaP,
                                            const float* __restrict__ wptP,
                                            const float* __restrict__ avgP,
                                            float* __restrict__ partW,
                                            float* __restrict__ partP) {
    __shared__ float2 tw_tab[40];
    __shared__ float wp_tab[40];
    float w = 1.f / (1.f + __expf(-wtP[0]));
    if (threadIdx.x < 40) {
        float tt = t_tild[threadIdx.x];
        tw_tab[threadIdx.x] = make_float2(__expf(tt), (1.f - w) * tt * LOG2E);
        wp_tab[threadIdx.x] = __expf(wptP[threadIdx.x]);
    }
    __syncthreads();
    float alpha = alphaP[0];
    float beta = betaP[0];
    float avg = avgP[0];
    float lavg = __log2f(avg + EPSf);
    bool b1 = (beta == 1.0f);

    int gid = blockIdx.x * WG + threadIdx.x;
    int p = gid >> 1;          // block-pair index
    int img = gid & 1;         // 0 = target, 1 = input  (== lane parity)
    int base20 = img * 20;
    int n = p >> 12, k = p & 4095;
    int bi = k >> 6, bj = k & 63;
    size_t off = (size_t)n * (IMG_H * IMG_W) + (size_t)(bi * 8) * IMG_W + bj * 8;
    const float* src = (img ? inp : tgt) + off;

    // row FFT state for ONE image: 64 named scalars
    DECL8(t0); DECL8(t1); DECL8(t2); DECL8(t3);
    DECL8(t4); DECL8(t5); DECL8(t6); DECL8(t7);
    LOADROW(src, 0, t0); LOADROW(src, 1, t1); LOADROW(src, 2, t2); LOADROW(src, 3, t3);
    LOADROW(src, 4, t4); LOADROW(src, 5, t5); LOADROW(src, 6, t6); LOADROW(src, 7, t7);

    float sumW = 0.f, sumP = 0.f;
    float lum = 0.f, omw_llum = 0.f;

    { // v = 0 : real column, component 0
        CFFT8M(X, t0_0, 0.f, t1_0, 0.f, t2_0, 0.f, t3_0, 0.f,
                  t4_0, 0.f, t5_0, 0.f, t6_0, 0.f, t7_0, 0.f)
        // lum from TARGET's DC amp (even lane owns it)
        float rr = X0r + EPSf, ii = X0i + EPSf;
        float myamp = FSQRT(fmaf(rr, rr, ii * ii));
        float oamp = dpp_xor1(myamp);
        float amp00 = img ? oamp : myamp;
        float llum = alpha * (__log2f(amp00 + EPSf) - lavg);
        lum = exp2f(llum);
        omw_llum = (1.f - w) * llum;
        COEFS2(0);
    }
    { // v = 1 : components 1 (re), 2 (im)
        CFFT8M(X, t0_1, t0_2, t1_1, t1_2, t2_1, t2_2, t3_1, t3_2,
                  t4_1, t4_2, t5_1, t5_2, t6_1, t6_2, t7_1, t7_2)
        COEFS2(1);
    }
    { // v = 2 : components 3, 4
        CFFT8M(X, t0_3, t0_4, t1_3, t1_4, t2_3, t2_4, t3_3, t3_4,
                  t4_3, t4_4, t5_3, t5_4, t6_3, t6_4, t7_3, t7_4)
        COEFS2(2);
    }
    { // v = 3 : components 5, 6
        CFFT8M(X, t0_5, t0_6, t1_5, t1_6, t2_5, t2_6, t3_5, t3_6,
                  t4_5, t4_6, t5_5, t5_6, t6_5, t6_6, t7_5, t7_6)
        COEFS2(3);
    }
    { // v = 4 : real column, component 7
        CFFT8M(X, t0_7, 0.f, t1_7, 0.f, t2_7, 0.f, t3_7, 0.f,
                  t4_7, 0.f, t5_7, 0.f, t6_7, 0.f, t7_7, 0.f)
        COEFS2(4);
    }

    if (b1) sumW += 20.f * 2.f * EPSf;   // fold per-term (+eps)^1 + eps

    float wW = wave_red(sumW);
    float wP = wave_red(sumP);
    __shared__ float redW[4], redP[4];
    if ((threadIdx.x & 63) == 0) { redW[threadIdx.x >> 6] = wW; redP[threadIdx.x >> 6] = wP; }
    __syncthreads();
    if (threadIdx.x == 0) {
        partW[blockIdx.x] = (redW[0] + redW[1]) + (redW[2] + redW[3]);
        partP[blockIdx.x] = (redP[0] + redP[1]) + (redP[2] + redP[3]);
    }
}

// ---------------- kernel D: per-image final ----------------------------------
__global__ __launch_bounds__(64) void kD(const float* __restrict__ partW,
                                         const float* __restrict__ partP,
                                         const float* __restrict__ betaP,
                                         float* __restrict__ out) {
    int n = threadIdx.x;
    float sW = 0.f, sP = 0.f;
#pragma unroll
    for (int c = 0; c < CHUNKS; c++) {
        sW += partW[n * CHUNKS + c];
        sP += partP[n * CHUNKS + c];
    }
    float beta = betaP[0];
    float wat = (beta == 1.0f) ? sW : __powf(sW, 1.0f / beta);
    out[n] = wat + sP;
}

extern "C" void kernel_launch(void* const* d_in, const int* in_sizes, int n_in,
                              void* d_out, int out_size, void* d_ws, size_t ws_size,
                              hipStream_t stream) {
    const float* inp    = (const float*)d_in[0];
    const float* tgt    = (const float*)d_in[1];
    const float* t_tild = (const float*)d_in[2];
    const float* alphaP = (const float*)d_in[3];
    const float* wtP    = (const float*)d_in[4];
    const float* betaP  = (const float*)d_in[5];
    const float* wptP   = (const float*)d_in[6];
    float* out = (float*)d_out;
    float* ws = (float*)d_ws;
    float* partA = ws;           // [1024]
    float* avgV  = ws + 1024;    // [1]
    float* partW = ws + 1056;    // [2048]
    float* partP = ws + 3104;    // [2048]

    hipLaunchKernelGGL(kA, dim3(NWG), dim3(WG), 0, stream, tgt, partA);
    hipLaunchKernelGGL(kB, dim3(1), dim3(1024), 0, stream, partA, avgV);
    hipLaunchKernelGGL(kC, dim3(NWG2), dim3(WG), 0, stream, tgt, inp, t_tild,
                       alphaP, wtP, betaP, wptP, avgV, partW, partP);
    hipLaunchKernelGGL(kD, dim3(1), dim3(64), 0, stream, partW, partP, betaP, out);
}

// Round 9
// 53.165 us; speedup vs baseline: 5.1472x; 1.0186x over previous
//
#include <hip/hip_runtime.h>
#include <math.h>

#define EPSf 1e-10f
#define IMG_N 64
#define IMG_H 512
#define IMG_W 512
#define KBLK 4096                  // 64x64 blocks per image
#define TOTAL_BLK (IMG_N * KBLK)   // 262144
#define WG 256
#define NWG (TOTAL_BLK / WG)       // 1024 (kA)
#define NWG2 (TOTAL_BLK * 2 / WG)  // 2048 (kC: 2 lanes per block-pair)
#define CHUNKS 32                  // kC workgroups per image (2048/64)

#define KCc 0.70710678118654752440f
#define SCc (1.0f / 64.0f)
#define LOG2E 1.44269504088896340736f

#define FSQRT(x) __builtin_amdgcn_sqrtf(x)
#define FRCP(x)  __builtin_amdgcn_rcpf(x)

// lane^1 exchange via DPP quad_perm [1,0,3,2] — pure VALU, no DS op
__device__ __forceinline__ float dpp_xor1(float x) {
    int i = __builtin_bit_cast(int, x);
    i = __builtin_amdgcn_mov_dpp(i, 0xB1, 0xF, 0xF, true);
    return __builtin_bit_cast(float, i);
}

__device__ __forceinline__ float wave_red(float v) {
#pragma unroll
    for (int o = 32; o > 0; o >>= 1) v += __shfl_down(v, o, 64);
    return v;
}

// ---------------- kernel A: per-block DC amplitude of target, partial sums ----
__global__ __launch_bounds__(WG) void kA(const float* __restrict__ tgt,
                                         float* __restrict__ partA) {
    int gid = blockIdx.x * WG + threadIdx.x;
    int n = gid >> 12;
    int k = gid & 4095;
    int bi = k >> 6, bj = k & 63;
    const float* p = tgt + (size_t)n * (IMG_H * IMG_W) + (size_t)(bi * 8) * IMG_W + bj * 8;
    float s = 0.f;
#pragma unroll
    for (int r = 0; r < 8; r++) {
        float4 a = *(const float4*)(p + (size_t)r * IMG_W);
        float4 b = *(const float4*)(p + (size_t)r * IMG_W + 4);
        s += ((a.x + a.y) + (a.z + a.w)) + ((b.x + b.y) + (b.z + b.w));
    }
    float dc = s * (1.0f / 64.0f);                 // rfft2 DC / b^2
    float amp = sqrtf((dc + EPSf) * (dc + EPSf) + EPSf * EPSf);
    float wv = wave_red(amp);
    __shared__ float red[4];
    if ((threadIdx.x & 63) == 0) red[threadIdx.x >> 6] = wv;
    __syncthreads();
    if (threadIdx.x == 0) partA[blockIdx.x] = (red[0] + red[1]) + (red[2] + red[3]);
}

// ---------------- kernel B: reduce 1024 partials -> avg_lum -------------------
__global__ __launch_bounds__(1024) void kB(const float* __restrict__ partA,
                                           float* __restrict__ avgOut) {
    float v = partA[threadIdx.x];
    float wv = wave_red(v);
    __shared__ float red[16];
    if ((threadIdx.x & 63) == 0) red[threadIdx.x >> 6] = wv;
    __syncthreads();
    if (threadIdx.x == 0) {
        float s = 0.f;
#pragma unroll
        for (int i = 0; i < 16; i++) s += red[i];
        avgOut[0] = s * (1.0f / (float)TOTAL_BLK);
    }
}

// row real FFT-8 -> 8 NAMED scalars [c0, c1r, c1i, c2r, c2i, c3r, c3i, c4], /64
#define ROWFFT(A, B, P) do { \
    float s02 = (A).x + (B).x, d02 = (A).x - (B).x; \
    float s26 = (A).z + (B).z, d26 = (A).z - (B).z; \
    float s13 = (A).y + (B).y, d13 = (A).y - (B).y; \
    float s37 = (A).w + (B).w, d37 = (A).w - (B).w; \
    float e0 = s02 + s26, e2 = s02 - s26; \
    float o0 = s13 + s37, o2 = s13 - s37; \
    float cp = KCc * (d13 - d37), cm = KCc * (d13 + d37); \
    P##_0 = SCc * (e0 + o0);  P##_1 = SCc * (d02 + cp); \
    P##_2 = SCc * (-d26 - cm); P##_3 = SCc * e2; \
    P##_4 = SCc * (-o2);      P##_5 = SCc * (d02 - cp); \
    P##_6 = SCc * (d26 - cm); P##_7 = SCc * (e0 - o0); \
} while (0)

#define DECL8(P) float P##_0, P##_1, P##_2, P##_3, P##_4, P##_5, P##_6, P##_7

#define LOADROW(ptr, r, P) do { \
    float4 A = *(const float4*)((ptr) + (size_t)(r) * IMG_W); \
    float4 B = *(const float4*)((ptr) + (size_t)(r) * IMG_W + 4); \
    ROWFFT(A, B, P); \
} while (0)

// complex FFT-8 on 16 scalar inputs -> 16 NAMED scalar outputs PFX0r..PFX7i
#define CFFT8M(PFX, x0r,x0i,x1r,x1i,x2r,x2i,x3r,x3i,x4r,x4i,x5r,x5i,x6r,x6i,x7r,x7i) \
    float PFX##0r, PFX##0i, PFX##1r, PFX##1i, PFX##2r, PFX##2i, PFX##3r, PFX##3i, \
          PFX##4r, PFX##4i, PFX##5r, PFX##5i, PFX##6r, PFX##6i, PFX##7r, PFX##7i; \
    { \
        float t0r = (x0r) + (x4r), t0i = (x0i) + (x4i); \
        float t1r = (x0r) - (x4r), t1i = (x0i) - (x4i); \
        float t2r = (x2r) + (x6r), t2i = (x2i) + (x6i); \
        float t3r = (x2r) - (x6r), t3i = (x2i) - (x6i); \
        float E0r = t0r + t2r, E0i = t0i + t2i; \
        float E2r = t0r - t2r, E2i = t0i - t2i; \
        float E1r = t1r + t3i, E1i = t1i - t3r; \
        float E3r = t1r - t3i, E3i = t1i + t3r; \
        float u0r = (x1r) + (x5r), u0i = (x1i) + (x5i); \
        float u1r = (x1r) - (x5r), u1i = (x1i) - (x5i); \
        float u2r = (x3r) + (x7r), u2i = (x3i) + (x7i); \
        float u3r = (x3r) - (x7r), u3i = (x3i) - (x7i); \
        float O0r = u0r + u2r, O0i = u0i + u2i; \
        float O2r = u0r - u2r, O2i = u0i - u2i; \
        float O1r = u1r + u3i, O1i = u1i - u3r; \
        float O3r = u1r - u3i, O3i = u1i + u3r; \
        float W1r = KCc * (O1r + O1i), W1i = KCc * (O1i - O1r); \
        float W2r = O2i,               W2i = -O2r; \
        float W3r = KCc * (O3i - O3r), W3i = -KCc * (O3r + O3i); \
        PFX##0r = E0r + O0r; PFX##0i = E0i + O0i; \
        PFX##1r = E1r + W1r; PFX##1i = E1i + W1i; \
        PFX##2r = E2r + W2r; PFX##2i = E2i + W2i; \
        PFX##3r = E3r + W3r; PFX##3i = E3i + W3i; \
        PFX##4r = E0r - O0r; PFX##4i = E0i - O0i; \
        PFX##5r = E1r - W1r; PFX##5i = E1i - W1i; \
        PFX##6r = E2r - W2r; PFX##6i = E2i - W2i; \
        PFX##7r = E3r - W3r; PFX##7i = E3i - W3i; \
    }

// fast acos: Abramowitz-Stegun 4.4.45 (3-term), max err ~6.7e-5 rad
__device__ __forceinline__ float acos_fast(float x) {
    float t = fabsf(x);
    float r = FSQRT(1.f - t);
    float p = fmaf(fmaf(fmaf(-0.0187293f, t, 0.0742610f), t, -0.2121144f), t, 1.5707288f);
    float ac = r * p;
    return (x < 0.f) ? (3.14159265358979f - ac) : ac;
}

// one coefficient pair contribution. own=(oR,oI) this lane's image; rec=(rR,rI)
// partner's image. img=0: own is target; img=1: rec is target.
// q = {t, (1-w)*log2(t), wp, 0} prefetched from LDS.
__device__ __forceinline__ void coef2(float oR, float oI, float rR, float rI,
                                      float4 q, int img,
                                      float lum, float omw_llum, float w,
                                      bool b1, float beta,
                                      float& sumW, float& sumP) {
    float oRe = oR + EPSf, oIe = oI + EPSf;
    float rRe = rR + EPSf, rIe = rI + EPSf;
    float aO = FSQRT(fmaf(oRe, oRe, oIe * oIe));
    float aR = FSQRT(fmaf(rRe, rRe, rIe * rIe));
    float a0 = img ? aR : aO;                       // target amplitude
    float dx = fabsf(aO - aR);
    // bb = (a0+eps)^w * t_l^(1-w) via single log2/exp2
    float l0 = __log2f(a0 + EPSf);
    float bb = exp2f(fmaf(w, l0, q.y + omw_llum));
    float t_l = q.x * lum;
    float e = __expf(bb - t_l);
    // s = (t_l + bb*e)/(1+e)  =>  x = dx*(1+e)/(t_l + bb*e): one rcp
    float x = dx * (1.f + e) * FRCP(fmaf(bb, e, t_l));
    if (b1) sumW += x;                              // epsilons folded in at end
    else    sumW += __powf(x + EPSf, beta) + EPSf;
    // phase: cos(p0-p1). norms ~= (aO*aR)^2 (eps-order difference, tol 967)
    float dot = fmaf(oRe, rRe, oI * rI);
    float cosd = dot * FRCP(fmaxf(aO * aR, 1e-30f)) * (1.f - 1e-7f);
    cosd = fminf(fmaxf(cosd, -1.f), 1.f);
    sumP = fmaf(acos_fast(cosd), q.z, sumP);
}

// half-exchange one slot pair: even lane owns u=S (sends u=S+4), odd owns u=S+4
#define PAIRC(Q, LOr, LOi, HIr, HIi) do { \
    float sdr = img ? (LOr) : (HIr), sdi = img ? (LOi) : (HIi); \
    float rcr = dpp_xor1(sdr), rci = dpp_xor1(sdi); \
    float owr = img ? (HIr) : (LOr), owi = img ? (HIi) : (LOi); \
    coef2(owr, owi, rcr, rci, (Q), img, lum, omw_llum, w, b1, beta, sumW, sumP); \
} while (0)

// prefetch this column's 4 table entries (before the column FFT hides latency)
#define PREFQ(V) \
    float4 q0 = tab4[base20 + 0 * 5 + (V)]; \
    float4 q1 = tab4[base20 + 1 * 5 + (V)]; \
    float4 q2 = tab4[base20 + 2 * 5 + (V)]; \
    float4 q3 = tab4[base20 + 3 * 5 + (V)];

#define COEFS2() do { \
    PAIRC(q0, X0r, X0i, X4r, X4i); \
    PAIRC(q1, X1r, X1i, X5r, X5i); \
    PAIRC(q2, X2r, X2i, X6r, X6i); \
    PAIRC(q3, X3r, X3i, X7r, X7i); \
} while (0)

// ---------------- kernel C: main fused compute (2 lanes per block-pair) -------
__global__ __launch_bounds__(WG, 2) void kC(const float* __restrict__ tgt,
                                            const float* __restrict__ inp,
                                            const float* __restrict__ t_tild,
                                            const float* __restrict__ alphaP,
                                            const float* __restrict__ wtP,
                                            const float* __restrict__ betaP,
                                            const float* __restrict__ wptP,
                                            const float* __restrict__ avgP,
                                            float* __restrict__ partW,
                                            float* __restrict__ partP) {
    __shared__ float4 tab4[40];    // {t, (1-w)*log2 t, wp, 0}
    float w = 1.f / (1.f + __expf(-wtP[0]));
    if (threadIdx.x < 40) {
        float tt = t_tild[threadIdx.x];
        tab4[threadIdx.x] = make_float4(__expf(tt), (1.f - w) * tt * LOG2E,
                                        __expf(wptP[threadIdx.x]), 0.f);
    }
    __syncthreads();
    float alpha = alphaP[0];
    float beta = betaP[0];
    float avg = avgP[0];
    float lavg = __log2f(avg + EPSf);
    bool b1 = (beta == 1.0f);

    int gid = blockIdx.x * WG + threadIdx.x;
    int p = gid >> 1;          // block-pair index
    int img = gid & 1;         // 0 = target, 1 = input  (== lane parity)
    int base20 = img * 20;
    int n = p >> 12, k = p & 4095;
    int bi = k >> 6, bj = k & 63;
    size_t off = (size_t)n * (IMG_H * IMG_W) + (size_t)(bi * 8) * IMG_W + bj * 8;
    const float* src = (img ? inp : tgt) + off;

    // row FFT state for ONE image: 64 named scalars
    DECL8(t0); DECL8(t1); DECL8(t2); DECL8(t3);
    DECL8(t4); DECL8(t5); DECL8(t6); DECL8(t7);
    LOADROW(src, 0, t0); LOADROW(src, 1, t1); LOADROW(src, 2, t2); LOADROW(src, 3, t3);
    LOADROW(src, 4, t4); LOADROW(src, 5, t5); LOADROW(src, 6, t6); LOADROW(src, 7, t7);

    float sumW = 0.f, sumP = 0.f;
    float lum = 0.f, omw_llum = 0.f;

    { // v = 0 : real column, component 0
        PREFQ(0)
        CFFT8M(X, t0_0, 0.f, t1_0, 0.f, t2_0, 0.f, t3_0, 0.f,
                  t4_0, 0.f, t5_0, 0.f, t6_0, 0.f, t7_0, 0.f)
        // lum from TARGET's DC amp (even lane owns it)
        float rr = X0r + EPSf, ii = X0i + EPSf;
        float myamp = FSQRT(fmaf(rr, rr, ii * ii));
        float oamp = dpp_xor1(myamp);
        float amp00 = img ? oamp : myamp;
        float llum = alpha * (__log2f(amp00 + EPSf) - lavg);
        lum = exp2f(llum);
        omw_llum = (1.f - w) * llum;
        COEFS2();
    }
    { // v = 1 : components 1 (re), 2 (im)
        PREFQ(1)
        CFFT8M(X, t0_1, t0_2, t1_1, t1_2, t2_1, t2_2, t3_1, t3_2,
                  t4_1, t4_2, t5_1, t5_2, t6_1, t6_2, t7_1, t7_2)
        COEFS2();
    }
    { // v = 2 : components 3, 4
        PREFQ(2)
        CFFT8M(X, t0_3, t0_4, t1_3, t1_4, t2_3, t2_4, t3_3, t3_4,
                  t4_3, t4_4, t5_3, t5_4, t6_3, t6_4, t7_3, t7_4)
        COEFS2();
    }
    { // v = 3 : components 5, 6
        PREFQ(3)
        CFFT8M(X, t0_5, t0_6, t1_5, t1_6, t2_5, t2_6, t3_5, t3_6,
                  t4_5, t4_6, t5_5, t5_6, t6_5, t6_6, t7_5, t7_6)
        COEFS2();
    }
    { // v = 4 : real column, component 7
        PREFQ(4)
        CFFT8M(X, t0_7, 0.f, t1_7, 0.f, t2_7, 0.f, t3_7, 0.f,
                  t4_7, 0.f, t5_7, 0.f, t6_7, 0.f, t7_7, 0.f)
        COEFS2();
    }

    if (b1) sumW += 20.f * 2.f * EPSf;   // fold per-term (+eps)^1 + eps

    float wW = wave_red(sumW);
    float wP = wave_red(sumP);
    __shared__ float redW[4], redP[4];
    if ((threadIdx.x & 63) == 0) { redW[threadIdx.x >> 6] = wW; redP[threadIdx.x >> 6] = wP; }
    __syncthreads();
    if (threadIdx.x == 0) {
        partW[blockIdx.x] = (redW[0] + redW[1]) + (redW[2] + redW[3]);
        partP[blockIdx.x] = (redP[0] + redP[1]) + (redP[2] + redP[3]);
    }
}

// ---------------- kernel D: per-image final ----------------------------------
__global__ __launch_bounds__(64) void kD(const float* __restrict__ partW,
                                         const float* __restrict__ partP,
                                         const float* __restrict__ betaP,
                                         float* __restrict__ out) {
    int n = threadIdx.x;
    float sW = 0.f, sP = 0.f;
#pragma unroll
    for (int c = 0; c < CHUNKS; c++) {
        sW += partW[n * CHUNKS + c];
        sP += partP[n * CHUNKS + c];
    }
    float beta = betaP[0];
    float wat = (beta == 1.0f) ? sW : __powf(sW, 1.0f / beta);
    out[n] = wat + sP;
}

extern "C" void kernel_launch(void* const* d_in, const int* in_sizes, int n_in,
                              void* d_out, int out_size, void* d_ws, size_t ws_size,
                              hipStream_t stream) {
    const float* inp    = (const float*)d_in[0];
    const float* tgt    = (const float*)d_in[1];
    const float* t_tild = (const float*)d_in[2];
    const float* alphaP = (const float*)d_in[3];
    const float* wtP    = (const float*)d_in[4];
    const float* betaP  = (const float*)d_in[5];
    const float* wptP   = (const float*)d_in[6];
    float* out = (float*)d_out;
    float* ws = (float*)d_ws;
    float* partA = ws;           // [1024]
    float* avgV  = ws + 1024;    // [1]
    float* partW = ws + 1056;    // [2048]
    float* partP = ws + 3104;    // [2048]

    hipLaunchKernelGGL(kA, dim3(NWG), dim3(WG), 0, stream, tgt, partA);
    hipLaunchKernelGGL(kB, dim3(1), dim3(1024), 0, stream, partA, avgV);
    hipLaunchKernelGGL(kC, dim3(NWG2), dim3(WG), 0, stream, tgt, inp, t_tild,
                       alphaP, wtP, betaP, wptP, avgV, partW, partP);
    hipLaunchKernelGGL(kD, dim3(1), dim3(64), 0, stream, partW, partP, betaP, out);
}

// Round 10
// 49.309 us; speedup vs baseline: 5.5496x; 1.0782x over previous
//
#include <hip/hip_runtime.h>
#include <math.h>

#define EPSf 1e-10f
#define IMG_N 64
#define IMG_H 512
#define IMG_W 512
#define KBLK 4096                  // 64x64 blocks per image
#define TOTAL_BLK (IMG_N * KBLK)   // 262144
#define WG 256
#define NWG (TOTAL_BLK / WG)       // 1024 (kA)
#define NWG2 (TOTAL_BLK * 2 / WG)  // 2048 (kC: 2 lanes per block-pair)
#define CHUNKS 32                  // kC workgroups per image (2048/64)

#define KCc 0.70710678118654752440f
#define SCc (1.0f / 64.0f)
#define LOG2E 1.44269504088896340736f

#define FSQRT(x) __builtin_amdgcn_sqrtf(x)
#define FRCP(x)  __builtin_amdgcn_rcpf(x)

// lane^1 exchange via DPP quad_perm [1,0,3,2] — pure VALU, no DS op
__device__ __forceinline__ float dpp_xor1(float x) {
    int i = __builtin_bit_cast(int, x);
    i = __builtin_amdgcn_mov_dpp(i, 0xB1, 0xF, 0xF, true);
    return __builtin_bit_cast(float, i);
}

__device__ __forceinline__ float wave_red(float v) {
#pragma unroll
    for (int o = 32; o > 0; o >>= 1) v += __shfl_down(v, o, 64);
    return v;
}

// ---------------- kernel A: per-block DC amplitude of target, partial sums ----
__global__ __launch_bounds__(WG) void kA(const float* __restrict__ tgt,
                                         float* __restrict__ partA) {
    int gid = blockIdx.x * WG + threadIdx.x;
    int n = gid >> 12;
    int k = gid & 4095;
    int bi = k >> 6, bj = k & 63;
    const float* p = tgt + (size_t)n * (IMG_H * IMG_W) + (size_t)(bi * 8) * IMG_W + bj * 8;
    float s = 0.f;
#pragma unroll
    for (int r = 0; r < 8; r++) {
        float4 a = *(const float4*)(p + (size_t)r * IMG_W);
        float4 b = *(const float4*)(p + (size_t)r * IMG_W + 4);
        s += ((a.x + a.y) + (a.z + a.w)) + ((b.x + b.y) + (b.z + b.w));
    }
    float dc = s * (1.0f / 64.0f);                 // rfft2 DC / b^2
    float amp = sqrtf((dc + EPSf) * (dc + EPSf) + EPSf * EPSf);
    float wv = wave_red(amp);
    __shared__ float red[4];
    if ((threadIdx.x & 63) == 0) red[threadIdx.x >> 6] = wv;
    __syncthreads();
    if (threadIdx.x == 0) partA[blockIdx.x] = (red[0] + red[1]) + (red[2] + red[3]);
}

// ---------------- kernel B: reduce 1024 partials -> avg_lum -------------------
__global__ __launch_bounds__(1024) void kB(const float* __restrict__ partA,
                                           float* __restrict__ avgOut) {
    float v = partA[threadIdx.x];
    float wv = wave_red(v);
    __shared__ float red[16];
    if ((threadIdx.x & 63) == 0) red[threadIdx.x >> 6] = wv;
    __syncthreads();
    if (threadIdx.x == 0) {
        float s = 0.f;
#pragma unroll
        for (int i = 0; i < 16; i++) s += red[i];
        avgOut[0] = s * (1.0f / (float)TOTAL_BLK);
    }
}

// row real FFT-8 -> 8 NAMED scalars [c0, c1r, c1i, c2r, c2i, c3r, c3i, c4], /64
#define ROWFFT(A, B, P) do { \
    float s02 = (A).x + (B).x, d02 = (A).x - (B).x; \
    float s26 = (A).z + (B).z, d26 = (A).z - (B).z; \
    float s13 = (A).y + (B).y, d13 = (A).y - (B).y; \
    float s37 = (A).w + (B).w, d37 = (A).w - (B).w; \
    float e0 = s02 + s26, e2 = s02 - s26; \
    float o0 = s13 + s37, o2 = s13 - s37; \
    float cp = KCc * (d13 - d37), cm = KCc * (d13 + d37); \
    P##_0 = SCc * (e0 + o0);  P##_1 = SCc * (d02 + cp); \
    P##_2 = SCc * (-d26 - cm); P##_3 = SCc * e2; \
    P##_4 = SCc * (-o2);      P##_5 = SCc * (d02 - cp); \
    P##_6 = SCc * (d26 - cm); P##_7 = SCc * (e0 - o0); \
} while (0)

#define DECL8(P) float P##_0, P##_1, P##_2, P##_3, P##_4, P##_5, P##_6, P##_7

#define LOADROW(ptr, r, P) do { \
    float4 A = *(const float4*)((ptr) + (size_t)(r) * IMG_W); \
    float4 B = *(const float4*)((ptr) + (size_t)(r) * IMG_W + 4); \
    ROWFFT(A, B, P); \
} while (0)

// complex FFT-8 on 16 scalar inputs -> 16 NAMED scalar outputs PFX0r..PFX7i
#define CFFT8M(PFX, x0r,x0i,x1r,x1i,x2r,x2i,x3r,x3i,x4r,x4i,x5r,x5i,x6r,x6i,x7r,x7i) \
    float PFX##0r, PFX##0i, PFX##1r, PFX##1i, PFX##2r, PFX##2i, PFX##3r, PFX##3i, \
          PFX##4r, PFX##4i, PFX##5r, PFX##5i, PFX##6r, PFX##6i, PFX##7r, PFX##7i; \
    { \
        float t0r = (x0r) + (x4r), t0i = (x0i) + (x4i); \
        float t1r = (x0r) - (x4r), t1i = (x0i) - (x4i); \
        float t2r = (x2r) + (x6r), t2i = (x2i) + (x6i); \
        float t3r = (x2r) - (x6r), t3i = (x2i) - (x6i); \
        float E0r = t0r + t2r, E0i = t0i + t2i; \
        float E2r = t0r - t2r, E2i = t0i - t2i; \
        float E1r = t1r + t3i, E1i = t1i - t3r; \
        float E3r = t1r - t3i, E3i = t1i + t3r; \
        float u0r = (x1r) + (x5r), u0i = (x1i) + (x5i); \
        float u1r = (x1r) - (x5r), u1i = (x1i) - (x5i); \
        float u2r = (x3r) + (x7r), u2i = (x3i) + (x7i); \
        float u3r = (x3r) - (x7r), u3i = (x3i) - (x7i); \
        float O0r = u0r + u2r, O0i = u0i + u2i; \
        float O2r = u0r - u2r, O2i = u0i - u2i; \
        float O1r = u1r + u3i, O1i = u1i - u3r; \
        float O3r = u1r - u3i, O3i = u1i + u3r; \
        float W1r = KCc * (O1r + O1i), W1i = KCc * (O1i - O1r); \
        float W2r = O2i,               W2i = -O2r; \
        float W3r = KCc * (O3i - O3r), W3i = -KCc * (O3r + O3i); \
        PFX##0r = E0r + O0r; PFX##0i = E0i + O0i; \
        PFX##1r = E1r + W1r; PFX##1i = E1i + W1i; \
        PFX##2r = E2r + W2r; PFX##2i = E2i + W2i; \
        PFX##3r = E3r + W3r; PFX##3i = E3i + W3i; \
        PFX##4r = E0r - O0r; PFX##4i = E0i - O0i; \
        PFX##5r = E1r - W1r; PFX##5i = E1i - W1i; \
        PFX##6r = E2r - W2r; PFX##6i = E2i - W2i; \
        PFX##7r = E3r - W3r; PFX##7i = E3i - W3i; \
    }

// one coefficient-pair contribution — SINGLE CODE COPY (noinline) to keep the
// kernel inside the 32KB L1 I-cache. Args/ret fit the register ABI (no scratch).
// own=(oR,oI) this lane's image; rec=(rR,rI) partner's. img=0: own is target.
__device__ __attribute__((noinline)) float2
coef2f(float oR, float oI, float rR, float rI,
       float tq, float lq, float pq,
       float lum, float omw_llum, float w, float beta,
       int img, int b1i) {
    float oRe = oR + EPSf, oIe = oI + EPSf;
    float rRe = rR + EPSf, rIe = rI + EPSf;
    float aO = FSQRT(fmaf(oRe, oRe, oIe * oIe));
    float aR = FSQRT(fmaf(rRe, rRe, rIe * rIe));
    float a0 = img ? aR : aO;                       // target amplitude
    float dx = fabsf(aO - aR);
    // bb = (a0+eps)^w * t_l^(1-w) via single log2/exp2
    float l0 = __log2f(a0 + EPSf);
    float bb = exp2f(fmaf(w, l0, lq + omw_llum));
    float t_l = tq * lum;
    float e = __expf(bb - t_l);
    // s = (t_l + bb*e)/(1+e)  =>  x = dx*(1+e)/(t_l + bb*e): one rcp
    float x = dx * (1.f + e) * FRCP(fmaf(bb, e, t_l));
    float dw = b1i ? x : (__powf(x + EPSf, beta) + EPSf);
    // phase: cos(p0-p1). norms ~= (aO*aR)^2 (eps-order difference, tol 967)
    float dot = fmaf(oRe, rRe, oI * rI);
    float cosd = dot * FRCP(fmaxf(aO * aR, 1e-30f)) * (1.f - 1e-7f);
    cosd = fminf(fmaxf(cosd, -1.f), 1.f);
    // fast acos: Abramowitz-Stegun 4.4.45, max err ~6.7e-5 rad
    float t = fabsf(cosd);
    float r = FSQRT(1.f - t);
    float pl = fmaf(fmaf(fmaf(-0.0187293f, t, 0.0742610f), t, -0.2121144f), t, 1.5707288f);
    float ac = r * pl;
    ac = (cosd < 0.f) ? (3.14159265358979f - ac) : ac;
    return make_float2(dw, ac * pq);
}

// half-exchange one slot pair: even lane owns u=S (sends u=S+4), odd owns u=S+4
#define PAIRC(Q, LOr, LOi, HIr, HIi) do { \
    float sdr = img ? (LOr) : (HIr), sdi = img ? (LOi) : (HIi); \
    float rcr = dpp_xor1(sdr), rci = dpp_xor1(sdi); \
    float owr = img ? (HIr) : (LOr), owi = img ? (HIi) : (LOi); \
    float2 dwp = coef2f(owr, owi, rcr, rci, (Q).x, (Q).y, (Q).z, \
                        lum, omw_llum, w, beta, img, b1i); \
    sumW += dwp.x; sumP += dwp.y; \
} while (0)

// prefetch this column's 4 table entries (before the column FFT hides latency)
#define PREFQ(V) \
    float4 q0 = tab4[base20 + 0 * 5 + (V)]; \
    float4 q1 = tab4[base20 + 1 * 5 + (V)]; \
    float4 q2 = tab4[base20 + 2 * 5 + (V)]; \
    float4 q3 = tab4[base20 + 3 * 5 + (V)];

#define COEFS2() do { \
    PAIRC(q0, X0r, X0i, X4r, X4i); \
    PAIRC(q1, X1r, X1i, X5r, X5i); \
    PAIRC(q2, X2r, X2i, X6r, X6i); \
    PAIRC(q3, X3r, X3i, X7r, X7i); \
} while (0)

// ---------------- kernel C: main fused compute (2 lanes per block-pair) -------
__global__ __launch_bounds__(WG, 4) void kC(const float* __restrict__ tgt,
                                            const float* __restrict__ inp,
                                            const float* __restrict__ t_tild,
                                            const float* __restrict__ alphaP,
                                            const float* __restrict__ wtP,
                                            const float* __restrict__ betaP,
                                            const float* __restrict__ wptP,
                                            const float* __restrict__ avgP,
                                            float* __restrict__ partW,
                                            float* __restrict__ partP) {
    __shared__ float4 tab4[40];    // {t, (1-w)*log2 t, wp, 0}
    float w = 1.f / (1.f + __expf(-wtP[0]));
    if (threadIdx.x < 40) {
        float tt = t_tild[threadIdx.x];
        tab4[threadIdx.x] = make_float4(__expf(tt), (1.f - w) * tt * LOG2E,
                                        __expf(wptP[threadIdx.x]), 0.f);
    }
    __syncthreads();
    float alpha = alphaP[0];
    float beta = betaP[0];
    float avg = avgP[0];
    float lavg = __log2f(avg + EPSf);
    int b1i = (beta == 1.0f) ? 1 : 0;

    int gid = blockIdx.x * WG + threadIdx.x;
    int p = gid >> 1;          // block-pair index
    int img = gid & 1;         // 0 = target, 1 = input  (== lane parity)
    int base20 = img * 20;
    int n = p >> 12, k = p & 4095;
    int bi = k >> 6, bj = k & 63;
    size_t off = (size_t)n * (IMG_H * IMG_W) + (size_t)(bi * 8) * IMG_W + bj * 8;
    const float* src = (img ? inp : tgt) + off;

    // row FFT state for ONE image: 64 named scalars
    DECL8(t0); DECL8(t1); DECL8(t2); DECL8(t3);
    DECL8(t4); DECL8(t5); DECL8(t6); DECL8(t7);
    LOADROW(src, 0, t0); LOADROW(src, 1, t1); LOADROW(src, 2, t2); LOADROW(src, 3, t3);
    LOADROW(src, 4, t4); LOADROW(src, 5, t5); LOADROW(src, 6, t6); LOADROW(src, 7, t7);

    float sumW = 0.f, sumP = 0.f;
    float lum = 0.f, omw_llum = 0.f;

    { // v = 0 : real column, component 0
        PREFQ(0)
        CFFT8M(X, t0_0, 0.f, t1_0, 0.f, t2_0, 0.f, t3_0, 0.f,
                  t4_0, 0.f, t5_0, 0.f, t6_0, 0.f, t7_0, 0.f)
        // lum from TARGET's DC amp (even lane owns it)
        float rr = X0r + EPSf, ii = X0i + EPSf;
        float myamp = FSQRT(fmaf(rr, rr, ii * ii));
        float oamp = dpp_xor1(myamp);
        float amp00 = img ? oamp : myamp;
        float llum = alpha * (__log2f(amp00 + EPSf) - lavg);
        lum = exp2f(llum);
        omw_llum = (1.f - w) * llum;
        COEFS2();
    }
    { // v = 1 : components 1 (re), 2 (im)
        PREFQ(1)
        CFFT8M(X, t0_1, t0_2, t1_1, t1_2, t2_1, t2_2, t3_1, t3_2,
                  t4_1, t4_2, t5_1, t5_2, t6_1, t6_2, t7_1, t7_2)
        COEFS2();
    }
    { // v = 2 : components 3, 4
        PREFQ(2)
        CFFT8M(X, t0_3, t0_4, t1_3, t1_4, t2_3, t2_4, t3_3, t3_4,
                  t4_3, t4_4, t5_3, t5_4, t6_3, t6_4, t7_3, t7_4)
        COEFS2();
    }
    { // v = 3 : components 5, 6
        PREFQ(3)
        CFFT8M(X, t0_5, t0_6, t1_5, t1_6, t2_5, t2_6, t3_5, t3_6,
                  t4_5, t4_6, t5_5, t5_6, t6_5, t6_6, t7_5, t7_6)
        COEFS2();
    }
    { // v = 4 : real column, component 7
        PREFQ(4)
        CFFT8M(X, t0_7, 0.f, t1_7, 0.f, t2_7, 0.f, t3_7, 0.f,
                  t4_7, 0.f, t5_7, 0.f, t6_7, 0.f, t7_7, 0.f)
        COEFS2();
    }

    if (b1i) sumW += 20.f * 2.f * EPSf;   // fold per-term (+eps)^1 + eps

    float wW = wave_red(sumW);
    float wP = wave_red(sumP);
    __shared__ float redW[4], redP[4];
    if ((threadIdx.x & 63) == 0) { redW[threadIdx.x >> 6] = wW; redP[threadIdx.x >> 6] = wP; }
    __syncthreads();
    if (threadIdx.x == 0) {
        partW[blockIdx.x] = (redW[0] + redW[1]) + (redW[2] + redW[3]);
        partP[blockIdx.x] = (redP[0] + redP[1]) + (redP[2] + redP[3]);
    }
}

// ---------------- kernel D: per-image final ----------------------------------
__global__ __launch_bounds__(64) void kD(const float* __restrict__ partW,
                                         const float* __restrict__ partP,
                                         const float* __restrict__ betaP,
                                         float* __restrict__ out) {
    int n = threadIdx.x;
    float sW = 0.f, sP = 0.f;
#pragma unroll
    for (int c = 0; c < CHUNKS; c++) {
        sW += partW[n * CHUNKS + c];
        sP += partP[n * CHUNKS + c];
    }
    float beta = betaP[0];
    float wat = (beta == 1.0f) ? sW : __powf(sW, 1.0f / beta);
    out[n] = wat + sP;
}

extern "C" void kernel_launch(void* const* d_in, const int* in_sizes, int n_in,
                              void* d_out, int out_size, void* d_ws, size_t ws_size,
                              hipStream_t stream) {
    const float* inp    = (const float*)d_in[0];
    const float* tgt    = (const float*)d_in[1];
    const float* t_tild = (const float*)d_in[2];
    const float* alphaP = (const float*)d_in[3];
    const float* wtP    = (const float*)d_in[4];
    const float* betaP  = (const float*)d_in[5];
    const float* wptP   = (const float*)d_in[6];
    float* out = (float*)d_out;
    float* ws = (float*)d_ws;
    float* partA = ws;           // [1024]
    float* avgV  = ws + 1024;    // [1]
    float* partW = ws + 1056;    // [2048]
    float* partP = ws + 3104;    // [2048]

    hipLaunchKernelGGL(kA, dim3(NWG), dim3(WG), 0, stream, tgt, partA);
    hipLaunchKernelGGL(kB, dim3(1), dim3(1024), 0, stream, partA, avgV);
    hipLaunchKernelGGL(kC, dim3(NWG2), dim3(WG), 0, stream, tgt, inp, t_tild,
                       alphaP, wtP, betaP, wptP, avgV, partW, partP);
    hipLaunchKernelGGL(kD, dim3(1), dim3(64), 0, stream, partW, partP, betaP, out);
}

// Round 11
// 45.742 us; speedup vs baseline: 5.9825x; 1.0780x over previous
//
#include <hip/hip_runtime.h>
#include <math.h>

#define EPSf 1e-10f
#define IMG_N 64
#define IMG_H 512
#define IMG_W 512
#define KBLK 4096                  // 64x64 blocks per image
#define TOTAL_BLK (IMG_N * KBLK)   // 262144
#define WG 256
#define NWG (TOTAL_BLK / WG)       // 1024 (kA)
#define NWG2 (TOTAL_BLK * 2 / WG)  // 2048 (kC: 2 lanes per block-pair)
#define CHUNKS 32                  // kC workgroups per image (2048/64)

#define KCc 0.70710678118654752440f
#define SCc (1.0f / 64.0f)
#define LOG2E 1.44269504088896340736f

#define FSQRT(x) __builtin_amdgcn_sqrtf(x)
#define FRCP(x)  __builtin_amdgcn_rcpf(x)

// lane^1 exchange via DPP quad_perm [1,0,3,2] — pure VALU, no DS op
__device__ __forceinline__ float dpp_xor1(float x) {
    int i = __builtin_bit_cast(int, x);
    i = __builtin_amdgcn_mov_dpp(i, 0xB1, 0xF, 0xF, true);
    return __builtin_bit_cast(float, i);
}

__device__ __forceinline__ float wave_red(float v) {
#pragma unroll
    for (int o = 32; o > 0; o >>= 1) v += __shfl_down(v, o, 64);
    return v;
}

// ---------------- kernel A: per-block DC amplitude of target, partial sums ----
__global__ __launch_bounds__(WG) void kA(const float* __restrict__ tgt,
                                         float* __restrict__ partA) {
    int gid = blockIdx.x * WG + threadIdx.x;
    int n = gid >> 12;
    int k = gid & 4095;
    int bi = k >> 6, bj = k & 63;
    const float* p = tgt + (size_t)n * (IMG_H * IMG_W) + (size_t)(bi * 8) * IMG_W + bj * 8;
    float s = 0.f;
#pragma unroll
    for (int r = 0; r < 8; r++) {
        float4 a = *(const float4*)(p + (size_t)r * IMG_W);
        float4 b = *(const float4*)(p + (size_t)r * IMG_W + 4);
        s += ((a.x + a.y) + (a.z + a.w)) + ((b.x + b.y) + (b.z + b.w));
    }
    float dc = s * (1.0f / 64.0f);                 // rfft2 DC / b^2
    float amp = sqrtf((dc + EPSf) * (dc + EPSf) + EPSf * EPSf);
    float wv = wave_red(amp);
    __shared__ float red[4];
    if ((threadIdx.x & 63) == 0) red[threadIdx.x >> 6] = wv;
    __syncthreads();
    if (threadIdx.x == 0) partA[blockIdx.x] = (red[0] + red[1]) + (red[2] + red[3]);
}

// row real FFT-8 -> 8 NAMED scalars [c0, c1r, c1i, c2r, c2i, c3r, c3i, c4], /64
#define ROWFFT(A, B, P) do { \
    float s02 = (A).x + (B).x, d02 = (A).x - (B).x; \
    float s26 = (A).z + (B).z, d26 = (A).z - (B).z; \
    float s13 = (A).y + (B).y, d13 = (A).y - (B).y; \
    float s37 = (A).w + (B).w, d37 = (A).w - (B).w; \
    float e0 = s02 + s26, e2 = s02 - s26; \
    float o0 = s13 + s37, o2 = s13 - s37; \
    float cp = KCc * (d13 - d37), cm = KCc * (d13 + d37); \
    P##_0 = SCc * (e0 + o0);  P##_1 = SCc * (d02 + cp); \
    P##_2 = SCc * (-d26 - cm); P##_3 = SCc * e2; \
    P##_4 = SCc * (-o2);      P##_5 = SCc * (d02 - cp); \
    P##_6 = SCc * (d26 - cm); P##_7 = SCc * (e0 - o0); \
} while (0)

#define DECL8(P) float P##_0, P##_1, P##_2, P##_3, P##_4, P##_5, P##_6, P##_7

#define LOADROW(ptr, r, P) do { \
    float4 A = *(const float4*)((ptr) + (size_t)(r) * IMG_W); \
    float4 B = *(const float4*)((ptr) + (size_t)(r) * IMG_W + 4); \
    ROWFFT(A, B, P); \
} while (0)

// complex FFT-8 on 16 scalar inputs -> 16 NAMED scalar outputs PFX0r..PFX7i
#define CFFT8M(PFX, x0r,x0i,x1r,x1i,x2r,x2i,x3r,x3i,x4r,x4i,x5r,x5i,x6r,x6i,x7r,x7i) \
    float PFX##0r, PFX##0i, PFX##1r, PFX##1i, PFX##2r, PFX##2i, PFX##3r, PFX##3i, \
          PFX##4r, PFX##4i, PFX##5r, PFX##5i, PFX##6r, PFX##6i, PFX##7r, PFX##7i; \
    { \
        float t0r = (x0r) + (x4r), t0i = (x0i) + (x4i); \
        float t1r = (x0r) - (x4r), t1i = (x0i) - (x4i); \
        float t2r = (x2r) + (x6r), t2i = (x2i) + (x6i); \
        float t3r = (x2r) - (x6r), t3i = (x2i) - (x6i); \
        float E0r = t0r + t2r, E0i = t0i + t2i; \
        float E2r = t0r - t2r, E2i = t0i - t2i; \
        float E1r = t1r + t3i, E1i = t1i - t3r; \
        float E3r = t1r - t3i, E3i = t1i + t3r; \
        float u0r = (x1r) + (x5r), u0i = (x1i) + (x5i); \
        float u1r = (x1r) - (x5r), u1i = (x1i) - (x5i); \
        float u2r = (x3r) + (x7r), u2i = (x3i) + (x7i); \
        float u3r = (x3r) - (x7r), u3i = (x3i) - (x7i); \
        float O0r = u0r + u2r, O0i = u0i + u2i; \
        float O2r = u0r - u2r, O2i = u0i - u2i; \
        float O1r = u1r + u3i, O1i = u1i - u3r; \
        float O3r = u1r - u3i, O3i = u1i + u3r; \
        float W1r = KCc * (O1r + O1i), W1i = KCc * (O1i - O1r); \
        float W2r = O2i,               W2i = -O2r; \
        float W3r = KCc * (O3i - O3r), W3i = -KCc * (O3r + O3i); \
        PFX##0r = E0r + O0r; PFX##0i = E0i + O0i; \
        PFX##1r = E1r + W1r; PFX##1i = E1i + W1i; \
        PFX##2r = E2r + W2r; PFX##2i = E2i + W2i; \
        PFX##3r = E3r + W3r; PFX##3i = E3i + W3i; \
        PFX##4r = E0r - O0r; PFX##4i = E0i - O0i; \
        PFX##5r = E1r - W1r; PFX##5i = E1i - W1i; \
        PFX##6r = E2r - W2r; PFX##6i = E2i - W2i; \
        PFX##7r = E3r - W3r; PFX##7i = E3i - W3i; \
    }

// TWO coefficient-pair contributions in one noinline call: single code copy
// (I$-friendly) but two independent chains interleaved inside (ILP restored).
// 20 dword args -> register ABI, no scratch.
__device__ __attribute__((noinline)) float2
coef2x2(float oRA, float oIA, float rRA, float rIA, float tA, float lA, float pA,
        float oRB, float oIB, float rRB, float rIB, float tB, float lB, float pB,
        float lum, float omw_llum, float w, float beta, int img, int b1i) {
    // --- amplitudes (A and B interleaved by the scheduler) ---
    float oReA = oRA + EPSf, oIeA = oIA + EPSf;
    float rReA = rRA + EPSf, rIeA = rIA + EPSf;
    float oReB = oRB + EPSf, oIeB = oIB + EPSf;
    float rReB = rRB + EPSf, rIeB = rIB + EPSf;
    float aOA = FSQRT(fmaf(oReA, oReA, oIeA * oIeA));
    float aRA = FSQRT(fmaf(rReA, rReA, rIeA * rIeA));
    float aOB = FSQRT(fmaf(oReB, oReB, oIeB * oIeB));
    float aRB = FSQRT(fmaf(rReB, rReB, rIeB * rIeB));
    float a0A = img ? aRA : aOA;
    float a0B = img ? aRB : aOB;
    float dxA = fabsf(aOA - aRA);
    float dxB = fabsf(aOB - aRB);
    // --- watson (bb via single log2/exp2) ---
    float l0A = __log2f(a0A + EPSf);
    float l0B = __log2f(a0B + EPSf);
    float bbA = exp2f(fmaf(w, l0A, lA + omw_llum));
    float bbB = exp2f(fmaf(w, l0B, lB + omw_llum));
    float tlA = tA * lum;
    float tlB = tB * lum;
    float eA = __expf(bbA - tlA);
    float eB = __expf(bbB - tlB);
    float xA = dxA * (1.f + eA) * FRCP(fmaf(bbA, eA, tlA));
    float xB = dxB * (1.f + eB) * FRCP(fmaf(bbB, eB, tlB));
    float dwA = b1i ? xA : (__powf(xA + EPSf, beta) + EPSf);
    float dwB = b1i ? xB : (__powf(xB + EPSf, beta) + EPSf);
    // --- phase ---
    float dotA = fmaf(oReA, rReA, oIA * rIA);
    float dotB = fmaf(oReB, rReB, oIB * rIB);
    float cdA = dotA * FRCP(fmaxf(aOA * aRA, 1e-30f)) * (1.f - 1e-7f);
    float cdB = dotB * FRCP(fmaxf(aOB * aRB, 1e-30f)) * (1.f - 1e-7f);
    cdA = fminf(fmaxf(cdA, -1.f), 1.f);
    cdB = fminf(fmaxf(cdB, -1.f), 1.f);
    // fast acos: Abramowitz-Stegun 4.4.45, max err ~6.7e-5 rad
    float tA2 = fabsf(cdA), tB2 = fabsf(cdB);
    float rA2 = FSQRT(1.f - tA2), rB2 = FSQRT(1.f - tB2);
    float plA = fmaf(fmaf(fmaf(-0.0187293f, tA2, 0.0742610f), tA2, -0.2121144f), tA2, 1.5707288f);
    float plB = fmaf(fmaf(fmaf(-0.0187293f, tB2, 0.0742610f), tB2, -0.2121144f), tB2, 1.5707288f);
    float acA = rA2 * plA;
    float acB = rB2 * plB;
    acA = (cdA < 0.f) ? (3.14159265358979f - acA) : acA;
    acB = (cdB < 0.f) ? (3.14159265358979f - acB) : acB;
    return make_float2(dwA + dwB, fmaf(acA, pA, acB * pB));
}

// two slot pairs per call: even lane owns u=S (sends u=S+4), odd owns u=S+4
#define PAIRC2(QA, LAr, LAi, HAr, HAi, QB, LBr, LBi, HBr, HBi) do { \
    float sAr = img ? (LAr) : (HAr), sAi = img ? (LAi) : (HAi); \
    float rAr = dpp_xor1(sAr), rAi = dpp_xor1(sAi); \
    float oAr = img ? (HAr) : (LAr), oAi = img ? (HAi) : (LAi); \
    float sBr = img ? (LBr) : (HBr), sBi = img ? (LBi) : (HBi); \
    float rBr = dpp_xor1(sBr), rBi = dpp_xor1(sBi); \
    float oBr = img ? (HBr) : (LBr), oBi = img ? (HBi) : (LBi); \
    float2 dwp = coef2x2(oAr, oAi, rAr, rAi, (QA).x, (QA).y, (QA).z, \
                         oBr, oBi, rBr, rBi, (QB).x, (QB).y, (QB).z, \
                         lum, omw_llum, w, beta, img, b1i); \
    sumW += dwp.x; sumP += dwp.y; \
} while (0)

// prefetch this column's 4 table entries (before the column FFT hides latency)
#define PREFQ(V) \
    float4 q0 = tab4[base20 + 0 * 5 + (V)]; \
    float4 q1 = tab4[base20 + 1 * 5 + (V)]; \
    float4 q2 = tab4[base20 + 2 * 5 + (V)]; \
    float4 q3 = tab4[base20 + 3 * 5 + (V)];

#define COEFS2() do { \
    PAIRC2(q0, X0r, X0i, X4r, X4i, q1, X1r, X1i, X5r, X5i); \
    PAIRC2(q2, X2r, X2i, X6r, X6i, q3, X3r, X3i, X7r, X7i); \
} while (0)

// ---------------- kernel C: main fused compute (2 lanes per block-pair) -------
// avg_lum reduction (was kernel kB) folded into the prologue: every WG
// redundantly reduces the 1024 kA partials in a fixed order (deterministic).
__global__ __launch_bounds__(WG, 4) void kC(const float* __restrict__ tgt,
                                            const float* __restrict__ inp,
                                            const float* __restrict__ t_tild,
                                            const float* __restrict__ alphaP,
                                            const float* __restrict__ wtP,
                                            const float* __restrict__ betaP,
                                            const float* __restrict__ wptP,
                                            const float* __restrict__ partA,
                                            float* __restrict__ partW,
                                            float* __restrict__ partP) {
    __shared__ float4 tab4[40];    // {t, (1-w)*log2 t, wp, 0}
    __shared__ float redA[4];
    float w = 1.f / (1.f + __expf(-wtP[0]));
    if (threadIdx.x < 40) {
        float tt = t_tild[threadIdx.x];
        tab4[threadIdx.x] = make_float4(__expf(tt), (1.f - w) * tt * LOG2E,
                                        __expf(wptP[threadIdx.x]), 0.f);
    }
    // in-kernel avg reduce (replaces kB): 4 strided loads + wave/LDS reduce
    {
        float v = partA[threadIdx.x] + partA[threadIdx.x + 256] +
                  partA[threadIdx.x + 512] + partA[threadIdx.x + 768];
        float wv = wave_red(v);
        if ((threadIdx.x & 63) == 0) redA[threadIdx.x >> 6] = wv;
    }
    __syncthreads();
    float avg = ((redA[0] + redA[1]) + (redA[2] + redA[3])) * (1.0f / (float)TOTAL_BLK);
    float alpha = alphaP[0];
    float beta = betaP[0];
    float lavg = __log2f(avg + EPSf);
    int b1i = (beta == 1.0f) ? 1 : 0;

    int gid = blockIdx.x * WG + threadIdx.x;
    int p = gid >> 1;          // block-pair index
    int img = gid & 1;         // 0 = target, 1 = input  (== lane parity)
    int base20 = img * 20;
    int n = p >> 12, k = p & 4095;
    int bi = k >> 6, bj = k & 63;
    size_t off = (size_t)n * (IMG_H * IMG_W) + (size_t)(bi * 8) * IMG_W + bj * 8;
    const float* src = (img ? inp : tgt) + off;

    // row FFT state for ONE image: 64 named scalars
    DECL8(t0); DECL8(t1); DECL8(t2); DECL8(t3);
    DECL8(t4); DECL8(t5); DECL8(t6); DECL8(t7);
    LOADROW(src, 0, t0); LOADROW(src, 1, t1); LOADROW(src, 2, t2); LOADROW(src, 3, t3);
    LOADROW(src, 4, t4); LOADROW(src, 5, t5); LOADROW(src, 6, t6); LOADROW(src, 7, t7);

    float sumW = 0.f, sumP = 0.f;
    float lum = 0.f, omw_llum = 0.f;

    { // v = 0 : real column, component 0
        PREFQ(0)
        CFFT8M(X, t0_0, 0.f, t1_0, 0.f, t2_0, 0.f, t3_0, 0.f,
                  t4_0, 0.f, t5_0, 0.f, t6_0, 0.f, t7_0, 0.f)
        // lum from TARGET's DC amp (even lane owns it)
        float rr = X0r + EPSf, ii = X0i + EPSf;
        float myamp = FSQRT(fmaf(rr, rr, ii * ii));
        float oamp = dpp_xor1(myamp);
        float amp00 = img ? oamp : myamp;
        float llum = alpha * (__log2f(amp00 + EPSf) - lavg);
        lum = exp2f(llum);
        omw_llum = (1.f - w) * llum;
        COEFS2();
    }
    { // v = 1 : components 1 (re), 2 (im)
        PREFQ(1)
        CFFT8M(X, t0_1, t0_2, t1_1, t1_2, t2_1, t2_2, t3_1, t3_2,
                  t4_1, t4_2, t5_1, t5_2, t6_1, t6_2, t7_1, t7_2)
        COEFS2();
    }
    { // v = 2 : components 3, 4
        PREFQ(2)
        CFFT8M(X, t0_3, t0_4, t1_3, t1_4, t2_3, t2_4, t3_3, t3_4,
                  t4_3, t4_4, t5_3, t5_4, t6_3, t6_4, t7_3, t7_4)
        COEFS2();
    }
    { // v = 3 : components 5, 6
        PREFQ(3)
        CFFT8M(X, t0_5, t0_6, t1_5, t1_6, t2_5, t2_6, t3_5, t3_6,
                  t4_5, t4_6, t5_5, t5_6, t6_5, t6_6, t7_5, t7_6)
        COEFS2();
    }
    { // v = 4 : real column, component 7
        PREFQ(4)
        CFFT8M(X, t0_7, 0.f, t1_7, 0.f, t2_7, 0.f, t3_7, 0.f,
                  t4_7, 0.f, t5_7, 0.f, t6_7, 0.f, t7_7, 0.f)
        COEFS2();
    }

    if (b1i) sumW += 20.f * 2.f * EPSf;   // fold per-term (+eps)^1 + eps

    float wW = wave_red(sumW);
    float wP = wave_red(sumP);
    __shared__ float redW[4], redP[4];
    if ((threadIdx.x & 63) == 0) { redW[threadIdx.x >> 6] = wW; redP[threadIdx.x >> 6] = wP; }
    __syncthreads();
    if (threadIdx.x == 0) {
        partW[blockIdx.x] = (redW[0] + redW[1]) + (redW[2] + redW[3]);
        partP[blockIdx.x] = (redP[0] + redP[1]) + (redP[2] + redP[3]);
    }
}

// ---------------- kernel D: per-image final ----------------------------------
__global__ __launch_bounds__(64) void kD(const float* __restrict__ partW,
                                         const float* __restrict__ partP,
                                         const float* __restrict__ betaP,
                                         float* __restrict__ out) {
    int n = threadIdx.x;
    float sW = 0.f, sP = 0.f;
#pragma unroll
    for (int c = 0; c < CHUNKS; c++) {
        sW += partW[n * CHUNKS + c];
        sP += partP[n * CHUNKS + c];
    }
    float beta = betaP[0];
    float wat = (beta == 1.0f) ? sW : __powf(sW, 1.0f / beta);
    out[n] = wat + sP;
}

extern "C" void kernel_launch(void* const* d_in, const int* in_sizes, int n_in,
                              void* d_out, int out_size, void* d_ws, size_t ws_size,
                              hipStream_t stream) {
    const float* inp    = (const float*)d_in[0];
    const float* tgt    = (const float*)d_in[1];
    const float* t_tild = (const float*)d_in[2];
    const float* alphaP = (const float*)d_in[3];
    const float* wtP    = (const float*)d_in[4];
    const float* betaP  = (const float*)d_in[5];
    const float* wptP   = (const float*)d_in[6];
    float* out = (float*)d_out;
    float* ws = (float*)d_ws;
    float* partA = ws;           // [1024]
    float* partW = ws + 1056;    // [2048]
    float* partP = ws + 3104;    // [2048]

    hipLaunchKernelGGL(kA, dim3(NWG), dim3(WG), 0, stream, tgt, partA);
    hipLaunchKernelGGL(kC, dim3(NWG2), dim3(WG), 0, stream, tgt, inp, t_tild,
                       alphaP, wtP, betaP, wptP, partA, partW, partP);
    hipLaunchKernelGGL(kD, dim3(1), dim3(64), 0, stream, partW, partP, betaP, out);
}